// Round 5
// baseline (3140.095 us; speedup 1.0000x reference)
//
#include <hip/hip_runtime.h>

#define N_NODES 100000
#define N_EDGES 800000
#define N_ETYPES 5
#define NUM_GRAPHS 64
#define IN_DIM 23
#define HID_DIM 128
#define OUT_DIM 64
#define CAP 15                 // srcs per row; row = [cnt | 15 src] = 64 B
#define ROWW 16
#define OVF_ENTRIES 16384

typedef unsigned short u16;
using short8 = __attribute__((ext_vector_type(8))) short;
using f32x4  = __attribute__((ext_vector_type(4))) float;

__device__ __forceinline__ float bf2f(u16 v) {
    union { unsigned u; float f; } x; x.u = ((unsigned)v) << 16; return x.f;
}
__device__ __forceinline__ u16 f2bf(float f) {
    union { float f; unsigned u; } x; x.f = f;
    unsigned r = x.u + 0x7fff + ((x.u >> 16) & 1);   // RNE
    return (u16)(r >> 16);
}

// ---------------- prep: W1t/W2t/b1s (bf16, transposed, zero-padded) ----------------
__global__ __launch_bounds__(256) void k_prep(const float* __restrict__ W1,
                                              const float* __restrict__ W2,
                                              const float* __restrict__ b1,
                                              u16* __restrict__ w1t,
                                              u16* __restrict__ w2t,
                                              float* __restrict__ b1s) {
    int stride = gridDim.x * 256;
    int g0 = blockIdx.x * 256 + threadIdx.x;
    for (int i = g0; i < HID_DIM * 160; i += stride) {       // w1t[hid][k], k=t*32+f
        int hid = i / 160, k = i - hid * 160;
        int t = k >> 5, f = k & 31;
        w1t[i] = (f < IN_DIM) ? f2bf(W1[((size_t)t * IN_DIM + f) * HID_DIM + hid]) : (u16)0;
    }
    for (int i = g0; i < N_ETYPES * OUT_DIM * HID_DIM; i += stride) { // w2t[t][out][k]
        int t = i >> 13, r = i & 8191;
        int out = r >> 7, k = r & 127;
        w2t[i] = f2bf(W2[((size_t)t * HID_DIM + k) * OUT_DIM + out]);
    }
    for (int i = g0; i < HID_DIM; i += stride) {
        float s = 0.f;
        #pragma unroll
        for (int t = 0; t < N_ETYPES; ++t) s += b1[t * HID_DIM + i];
        b1s[i] = s;
    }
}

// ---------------- xb: x -> bf16, padded to 24 cols ----------------
__global__ __launch_bounds__(256) void k_xb(const float* __restrict__ x,
                                            u16* __restrict__ xb) {
    int i = blockIdx.x * 256 + threadIdx.x;
    if (i >= N_NODES * 24) return;
    int n = i / 24, f = i - n * 24;
    xb[i] = (f < IN_DIM) ? f2bf(x[(size_t)n * IN_DIM + f]) : (u16)0;
}

// ---------------- adjacency fill: one 64B line per edge ----------------
__global__ __launch_bounds__(256) void k_fill(const int* __restrict__ edges,
                                              int* __restrict__ bucket,
                                              int* __restrict__ ovfn,
                                              long long* __restrict__ ovf) {
    int e = blockIdx.x * 256 + threadIdx.x;
    int t = blockIdx.y;
    if (e >= N_EDGES) return;
    int src = edges[((size_t)t * 2 + 0) * N_EDGES + e];
    int dst = edges[((size_t)t * 2 + 1) * N_EDGES + e];
    int row = t * N_NODES + dst;
    int pos = atomicAdd(&bucket[(size_t)row * ROWW], 1);
    if (pos < CAP) {
        bucket[(size_t)row * ROWW + 1 + pos] = src;
    } else {
        int oi = atomicAdd(ovfn, 1);
        if (oi < OVF_ENTRIES) ovf[oi] = ((long long)row << 32) | (unsigned)src;
    }
}

// ---------------- layer-1 gather: half-wave per (node,etype) -> acat bf16 [n][160] ----------------
__global__ __launch_bounds__(256) void k_gather1(const int* __restrict__ bucket,
                                                 const int* __restrict__ ovfn_g,
                                                 const long long* __restrict__ ovf,
                                                 const u16* __restrict__ xb,
                                                 u16* __restrict__ acat) {
    int tid = threadIdx.x;
    int n = blockIdx.x * 8 + (tid >> 5);
    int f = tid & 31;
    int t = blockIdx.y;
    int lanebase = tid & 32;
    int row = t * N_NODES + n;
    const int* brow = bucket + (size_t)row * ROWW;
    int bval = (f < ROWW) ? brow[f] : 0;                 // word0 = cnt, 1..15 = srcs
    int c = __shfl(bval, lanebase);
    int kmax = c < CAP ? c : CAP;
    float acc = (f < 24) ? bf2f(xb[(size_t)n * 24 + f]) : 0.f;   // self (col 23 = 0)
    float a0 = 0.f, a1 = 0.f;
    int k = 1;
    for (; k + 1 <= kmax; k += 2) {
        int s0 = __shfl(bval, lanebase + k);
        int s1 = __shfl(bval, lanebase + k + 1);
        if (f < 24) {
            a0 += bf2f(xb[(size_t)s0 * 24 + f]);
            a1 += bf2f(xb[(size_t)s1 * 24 + f]);
        }
    }
    if (k <= kmax) {
        int s0 = __shfl(bval, lanebase + k);
        if (f < 24) a0 += bf2f(xb[(size_t)s0 * 24 + f]);
    }
    acc += a0 + a1;
    if (c > CAP) {                                       // rare exact path
        int nov = *ovfn_g; if (nov > OVF_ENTRIES) nov = OVF_ENTRIES;
        for (int i = 0; i < nov; ++i) {
            long long v = ovf[i];
            if ((int)(v >> 32) == row && f < 24)
                acc += bf2f(xb[(size_t)(v & 0xffffffffLL) * 24 + f]);
        }
    }
    float inv = 1.0f / (float)(c + 1);
    acat[(size_t)n * 160 + t * 32 + f] = (f < 24) ? f2bf(acc * inv) : (u16)0;
}

// ---------------- fused GEMM chain: acat -> MFMA L1+relu (LDS) -> MFMA L2 -> g ----------------
__global__ __launch_bounds__(256) void k_gemm12(const u16* __restrict__ acat,
                                                const u16* __restrict__ w1t,
                                                const u16* __restrict__ w2t,
                                                const float* __restrict__ b1s,
                                                u16* __restrict__ g,
                                                int gt0, int gt1) {
    __shared__ u16 s_a[64 * 168];     // [64][160+8]  21504 B  (reused as s_out)
    __shared__ u16 s_h1[64 * 136];    // [64][128+8]  17408 B
    u16* s_out = s_a;                 // dead after A-frags are in registers
    int tid = threadIdx.x;
    int base = blockIdx.x * 64;

    // stage acat tile (coalesced ushort4)
    for (int i = tid; i < 64 * 40; i += 256) {
        int r = i / 40, c4 = (i - r * 40) * 4;
        ushort4 v = {0, 0, 0, 0};
        if (base + r < N_NODES)
            v = *(const ushort4*)&acat[(size_t)(base + r) * 160 + c4];
        *(ushort4*)&s_a[r * 168 + c4] = v;
    }
    __syncthreads();

    int l = tid & 63, w = tid >> 6;
    int lr = l & 15, lg = l >> 4;

    // ---- L1: h1 = relu(s_a @ W1t + b1s) ----
    short8 a5[5];
    #pragma unroll
    for (int ks = 0; ks < 5; ++ks)
        a5[ks] = *(const short8*)&s_a[(w * 16 + lr) * 168 + ks * 32 + lg * 8];
    {
        f32x4 acc[8];
        #pragma unroll
        for (int nt = 0; nt < 8; ++nt) acc[nt] = (f32x4){0.f, 0.f, 0.f, 0.f};
        #pragma unroll
        for (int nt = 0; nt < 8; ++nt) {
            #pragma unroll
            for (int ks = 0; ks < 5; ++ks) {
                short8 b = *(const short8*)&w1t[(nt * 16 + lr) * 160 + ks * 32 + lg * 8];
                acc[nt] = __builtin_amdgcn_mfma_f32_16x16x32_bf16(a5[ks], b, acc[nt], 0, 0, 0);
            }
        }
        #pragma unroll
        for (int nt = 0; nt < 8; ++nt) {
            float bias = b1s[nt * 16 + lr];
            #pragma unroll
            for (int r = 0; r < 4; ++r) {
                float h = acc[nt][r] + bias;
                s_h1[(w * 16 + lg * 4 + r) * 136 + nt * 16 + lr] = f2bf(h > 0.f ? h : 0.f);
            }
        }
    }
    __syncthreads();

    // ---- L2: per etype, g_t = h1 @ W2t ----
    short8 a2[4];
    #pragma unroll
    for (int ks = 0; ks < 4; ++ks)
        a2[ks] = *(const short8*)&s_h1[(w * 16 + lr) * 136 + ks * 32 + lg * 8];
    for (int t = gt0; t < gt1; ++t) {
        f32x4 acc2[4];
        #pragma unroll
        for (int nt = 0; nt < 4; ++nt) acc2[nt] = (f32x4){0.f, 0.f, 0.f, 0.f};
        #pragma unroll
        for (int nt = 0; nt < 4; ++nt) {
            #pragma unroll
            for (int ks = 0; ks < 4; ++ks) {
                short8 b = *(const short8*)&w2t[((size_t)t * OUT_DIM + nt * 16 + lr) * HID_DIM + ks * 32 + lg * 8];
                acc2[nt] = __builtin_amdgcn_mfma_f32_16x16x32_bf16(a2[ks], b, acc2[nt], 0, 0, 0);
            }
        }
        __syncthreads();          // prev s_out consumers done
        #pragma unroll
        for (int nt = 0; nt < 4; ++nt)
            #pragma unroll
            for (int r = 0; r < 4; ++r)
                s_out[(w * 16 + lg * 4 + r) * 72 + nt * 16 + lr] = f2bf(acc2[nt][r]);
        __syncthreads();
        size_t pb = (size_t)(t - gt0) * N_NODES;
        #pragma unroll
        for (int j = 0; j < 4; ++j) {
            int flat = j * 256 + tid;
            int rrow = flat >> 4, c4 = (flat & 15) * 4;
            int n = base + rrow;
            if (n < N_NODES)
                *(ushort4*)&g[(pb + n) * OUT_DIM + c4] = *(const ushort4*)&s_out[rrow * 72 + c4];
        }
    }
}

// ---------------- layer-2 gather: wave per node, etype range, h2 bf16 ----------------
__global__ __launch_bounds__(256) void k_gather2f(const int* __restrict__ bucket,
                                                  const int* __restrict__ ovfn_g,
                                                  const long long* __restrict__ ovf,
                                                  const u16* __restrict__ g,
                                                  u16* __restrict__ h2,
                                                  int t0, int tcnt, int add) {
    int n = blockIdx.x * 4 + (threadIdx.x >> 6);
    int lane = threadIdx.x & 63;
    float acc = 0.f;
    for (int tc = 0; tc < tcnt; ++tc) {
        int row = (t0 + tc) * N_NODES + n;
        const int* brow = bucket + (size_t)row * ROWW;
        int bval = (lane < ROWW) ? brow[lane] : 0;
        int c = __shfl(bval, 0);
        int kmax = c < CAP ? c : CAP;
        const u16* gp = g + (size_t)tc * N_NODES * OUT_DIM;
        float s = bf2f(gp[(size_t)n * OUT_DIM + lane]);   // self
        float s0 = 0.f, s1 = 0.f;
        int k = 1;
        for (; k + 1 <= kmax; k += 2) {
            int p0 = __shfl(bval, k);
            int p1 = __shfl(bval, k + 1);
            s0 += bf2f(gp[(size_t)p0 * OUT_DIM + lane]);
            s1 += bf2f(gp[(size_t)p1 * OUT_DIM + lane]);
        }
        if (k <= kmax) {
            int p0 = __shfl(bval, k);
            s0 += bf2f(gp[(size_t)p0 * OUT_DIM + lane]);
        }
        s += s0 + s1;
        if (c > CAP) {
            int nov = *ovfn_g; if (nov > OVF_ENTRIES) nov = OVF_ENTRIES;
            for (int i = 0; i < nov; ++i) {
                long long v = ovf[i];
                if ((int)(v >> 32) == row)
                    s += bf2f(gp[(size_t)(v & 0xffffffffLL) * OUT_DIM + lane]);
            }
        }
        acc += s / (float)(c + 1);
    }
    size_t oi = (size_t)n * OUT_DIM + lane;
    h2[oi] = f2bf(add ? bf2f(h2[oi]) + acc : acc);
}

// ---------------- pooling ----------------
__global__ __launch_bounds__(256) void k_pool(const u16* __restrict__ h2,
                                              const int* __restrict__ gids,
                                              const float* __restrict__ b2,
                                              float* __restrict__ out) {
    __shared__ float red[4][OUT_DIM];
    int gid = blockIdx.x;
    int lo = 0, hi = N_NODES;
    while (lo < hi) { int mid = (lo + hi) >> 1; if (gids[mid] < gid) lo = mid + 1; else hi = mid; }
    int start = lo;
    hi = N_NODES;
    while (lo < hi) { int mid = (lo + hi) >> 1; if (gids[mid] < gid + 1) lo = mid + 1; else hi = mid; }
    int end = lo;
    int count = end - start;
    int r = threadIdx.x >> 6, j = threadIdx.x & 63;
    float acc = 0.f;
    for (int n = start + r; n < end; n += 4)
        acc += bf2f(h2[(size_t)n * OUT_DIM + j]);
    red[r][j] = acc;
    __syncthreads();
    if (r == 0) {
        float total = red[0][j] + red[1][j] + red[2][j] + red[3][j];
        float b = 0.f;
        #pragma unroll
        for (int t = 0; t < N_ETYPES; ++t) b += b2[t * OUT_DIM + j];
        float c = (float)count;
        out[gid * OUT_DIM + j] = (total + c * b) / fmaxf(c, 1.0f);
    }
}

extern "C" void kernel_launch(void* const* d_in, const int* in_sizes, int n_in,
                              void* d_out, int out_size, void* d_ws, size_t ws_size,
                              hipStream_t stream) {
    const float* x    = (const float*)d_in[0];
    const int*   edges= (const int*)d_in[1];
    const int*   gids = (const int*)d_in[2];
    const float* W1   = (const float*)d_in[3];
    const float* b1   = (const float*)d_in[4];
    const float* W2   = (const float*)d_in[5];
    const float* b2   = (const float*)d_in[6];
    float* out = (float*)d_out;

    // word-offset workspace layout
    int*       bucket = (int*)d_ws;                         // 8,000,000 (500k x 16)
    int*       ovfn   = bucket + 8000000;                   // 1 (pad to 8,000,016)
    long long* ovf    = (long long*)(bucket + 8000016);     // 32,768 words
    u16*       xb     = (u16*)(bucket + 8032784);           // 1,200,000 words
    u16*       w1t    = (u16*)(bucket + 9232784);           // 10,240 words
    u16*       w2t    = (u16*)(bucket + 9243024);           // 20,480 words
    float*     b1s    = (float*)(bucket + 9263504);         // 128 (pad to 9,263,648)
    u16*       acat   = (u16*)(bucket + 9263648);           // 8,000,000 words
    u16*       g      = (u16*)(bucket + 17263648);          // 5 planes: 16M words / 3: 9.6M
    size_t need_single = 36463648ULL * 4;                   // 145.9 MB
    bool   single = ws_size >= need_single;
    u16*   h2 = (u16*)(bucket + (single ? 33263648 : 26863648));

    hipMemsetAsync(bucket, 0, 8000016ULL * 4, stream);      // cnts + ovfn (slots don't care)

    k_prep<<<80, 256, 0, stream>>>(W1, W2, b1, w1t, w2t, b1s);
    k_xb<<<(N_NODES * 24 + 255) / 256, 256, 0, stream>>>(x, xb);
    k_fill<<<dim3((N_EDGES + 255) / 256, N_ETYPES), 256, 0, stream>>>(edges, bucket, ovfn, ovf);

    k_gather1<<<dim3(N_NODES / 8, N_ETYPES), 256, 0, stream>>>(bucket, ovfn, ovf, xb, acat);

    int nblk = (N_NODES + 63) / 64;
    if (single) {
        k_gemm12<<<nblk, 256, 0, stream>>>(acat, w1t, w2t, b1s, g, 0, 5);
        k_gather2f<<<N_NODES / 4, 256, 0, stream>>>(bucket, ovfn, ovf, g, h2, 0, 5, 0);
    } else {
        k_gemm12<<<nblk, 256, 0, stream>>>(acat, w1t, w2t, b1s, g, 0, 3);
        k_gather2f<<<N_NODES / 4, 256, 0, stream>>>(bucket, ovfn, ovf, g, h2, 0, 3, 0);
        k_gemm12<<<nblk, 256, 0, stream>>>(acat, w1t, w2t, b1s, g, 3, 5);
        k_gather2f<<<N_NODES / 4, 256, 0, stream>>>(bucket, ovfn, ovf, g, h2, 3, 2, 1);
    }
    k_pool<<<NUM_GRAPHS, 256, 0, stream>>>(h2, gids, b2, out);
}

// Round 6
// 632.987 us; speedup vs baseline: 4.9608x; 4.9608x over previous
//
#include <hip/hip_runtime.h>

#define N_NODES 100000
#define N_EDGES 800000
#define N_ETYPES 5
#define NUM_GRAPHS 64
#define IN_DIM 23
#define HID_DIM 128
#define OUT_DIM 64
#define CAP 23                 // srcs per row; row = [cnt | 23 src] = 96 B
#define ROWW 24
#define OVF_ENTRIES 8192       // expected ~2 entries at CAP=23 (Poisson(8) tail)

typedef unsigned short u16;
using short8 = __attribute__((ext_vector_type(8))) short;
using f32x4  = __attribute__((ext_vector_type(4))) float;

__device__ __forceinline__ float bf2f(u16 v) {
    union { unsigned u; float f; } x; x.u = ((unsigned)v) << 16; return x.f;
}
__device__ __forceinline__ u16 f2bf(float f) {
    union { float f; unsigned u; } x; x.f = f;
    unsigned r = x.u + 0x7fff + ((x.u >> 16) & 1);   // RNE
    return (u16)(r >> 16);
}

// ---------------- prep: W1t/W2t/b1s (bf16, transposed, zero-padded) ----------------
__global__ __launch_bounds__(256) void k_prep(const float* __restrict__ W1,
                                              const float* __restrict__ W2,
                                              const float* __restrict__ b1,
                                              u16* __restrict__ w1t,
                                              u16* __restrict__ w2t,
                                              float* __restrict__ b1s) {
    int stride = gridDim.x * 256;
    int g0 = blockIdx.x * 256 + threadIdx.x;
    for (int i = g0; i < HID_DIM * 160; i += stride) {       // w1t[hid][k], k=t*32+f
        int hid = i / 160, k = i - hid * 160;
        int t = k >> 5, f = k & 31;
        w1t[i] = (f < IN_DIM) ? f2bf(W1[((size_t)t * IN_DIM + f) * HID_DIM + hid]) : (u16)0;
    }
    for (int i = g0; i < N_ETYPES * OUT_DIM * HID_DIM; i += stride) { // w2t[t][out][k]
        int t = i >> 13, r = i & 8191;
        int out = r >> 7, k = r & 127;
        w2t[i] = f2bf(W2[((size_t)t * HID_DIM + k) * OUT_DIM + out]);
    }
    for (int i = g0; i < HID_DIM; i += stride) {
        float s = 0.f;
        #pragma unroll
        for (int t = 0; t < N_ETYPES; ++t) s += b1[t * HID_DIM + i];
        b1s[i] = s;
    }
}

// ---------------- xb: x -> bf16, padded to 32 cols (64B rows) ----------------
__global__ __launch_bounds__(256) void k_xb(const float* __restrict__ x,
                                            u16* __restrict__ xb) {
    int i = blockIdx.x * 256 + threadIdx.x;
    if (i >= N_NODES * 32) return;
    int n = i >> 5, f = i & 31;
    xb[i] = (f < IN_DIM) ? f2bf(x[(size_t)n * IN_DIM + f]) : (u16)0;
}

// ---------------- adjacency fill: ~one 96B row per edge ----------------
__global__ __launch_bounds__(256) void k_fill(const int* __restrict__ edges,
                                              int* __restrict__ bucket,
                                              int* __restrict__ ovfn,
                                              long long* __restrict__ ovf) {
    int e = blockIdx.x * 256 + threadIdx.x;
    int t = blockIdx.y;
    if (e >= N_EDGES) return;
    int src = edges[((size_t)t * 2 + 0) * N_EDGES + e];
    int dst = edges[((size_t)t * 2 + 1) * N_EDGES + e];
    int row = t * N_NODES + dst;
    int pos = atomicAdd(&bucket[(size_t)row * ROWW], 1);
    if (pos < CAP) {
        bucket[(size_t)row * ROWW + 1 + pos] = src;
    } else {
        int oi = atomicAdd(ovfn, 1);
        if (oi < OVF_ENTRIES) ovf[oi] = ((long long)row << 32) | (unsigned)src;
    }
}

// ---------------- layer-1 gather: half-wave per (node,etype) -> acat bf16 [n][120] ----------------
__global__ __launch_bounds__(256) void k_gather1(const int* __restrict__ bucket,
                                                 const int* __restrict__ ovfn_g,
                                                 const long long* __restrict__ ovf,
                                                 const u16* __restrict__ xb,
                                                 u16* __restrict__ acat) {
    int tid = threadIdx.x;
    int n = blockIdx.x * 8 + (tid >> 5);
    int f = tid & 31;
    int t = blockIdx.y;
    int lanebase = tid & 32;
    int row = t * N_NODES + n;
    const int* brow = bucket + (size_t)row * ROWW;
    int bval = (f < ROWW) ? brow[f] : 0;          // word0 = cnt, 1..23 = srcs
    int c = __shfl(bval, lanebase);
    int kmax = c < CAP ? c : CAP;
    float acc = bf2f(xb[(size_t)n * 32 + f]);     // gcn self (pad cols are 0)
    float a0 = 0.f, a1 = 0.f, a2 = 0.f, a3 = 0.f;
    int k = 1;
    for (; k + 3 <= kmax; k += 4) {
        int s0 = __shfl(bval, lanebase + k);
        int s1 = __shfl(bval, lanebase + k + 1);
        int s2 = __shfl(bval, lanebase + k + 2);
        int s3 = __shfl(bval, lanebase + k + 3);
        a0 += bf2f(xb[(size_t)s0 * 32 + f]);
        a1 += bf2f(xb[(size_t)s1 * 32 + f]);
        a2 += bf2f(xb[(size_t)s2 * 32 + f]);
        a3 += bf2f(xb[(size_t)s3 * 32 + f]);
    }
    for (; k <= kmax; ++k) {
        int s0 = __shfl(bval, lanebase + k);
        a0 += bf2f(xb[(size_t)s0 * 32 + f]);
    }
    acc += (a0 + a1) + (a2 + a3);
    if (c > CAP) {                                // ~2 rows in 500k: negligible
        int nov = *ovfn_g; if (nov > OVF_ENTRIES) nov = OVF_ENTRIES;
        for (int i = 0; i < nov; ++i) {
            long long v = ovf[i];
            if ((int)(v >> 32) == row)
                acc += bf2f(xb[(size_t)(v & 0xffffffffLL) * 32 + f]);
        }
    }
    if (f < 24) acat[(size_t)n * 120 + t * 24 + f] = f2bf(acc / (float)(c + 1));
}

// ---------------- fused GEMM chain: acat -> MFMA L1+relu (LDS) -> MFMA L2 -> g ----------------
__global__ __launch_bounds__(256) void k_gemm12(const u16* __restrict__ acat,
                                                const u16* __restrict__ w1t,
                                                const u16* __restrict__ w2t,
                                                const float* __restrict__ b1s,
                                                u16* __restrict__ g,
                                                int gt0, int gt1) {
    __shared__ u16 s_a[64 * 168];     // [64][160+8]  21504 B  (reused as s_out)
    __shared__ u16 s_h1[64 * 136];    // [64][128+8]  17408 B
    u16* s_out = s_a;                 // dead after A-frags are in registers
    int tid = threadIdx.x;
    int base = blockIdx.x * 64;

    // stage acat tile: expand [120] packed -> [160] zero-padded (coalesced ushort4)
    for (int i = tid; i < 64 * 40; i += 256) {
        int r = i / 40, col4 = i - r * 40;        // col4 in [0,40)
        int t = col4 >> 3, q4 = col4 & 7;
        ushort4 v = {0, 0, 0, 0};
        if (q4 < 6 && base + r < N_NODES)
            v = *(const ushort4*)&acat[(size_t)(base + r) * 120 + t * 24 + q4 * 4];
        *(ushort4*)&s_a[r * 168 + t * 32 + q4 * 4] = v;
    }
    __syncthreads();

    int l = tid & 63, w = tid >> 6;
    int lr = l & 15, lg = l >> 4;

    // ---- L1: h1 = relu(s_a @ W1t + b1s) ----
    short8 a5[5];
    #pragma unroll
    for (int ks = 0; ks < 5; ++ks)
        a5[ks] = *(const short8*)&s_a[(w * 16 + lr) * 168 + ks * 32 + lg * 8];
    {
        f32x4 acc[8];
        #pragma unroll
        for (int nt = 0; nt < 8; ++nt) acc[nt] = (f32x4){0.f, 0.f, 0.f, 0.f};
        #pragma unroll
        for (int nt = 0; nt < 8; ++nt) {
            #pragma unroll
            for (int ks = 0; ks < 5; ++ks) {
                short8 b = *(const short8*)&w1t[(nt * 16 + lr) * 160 + ks * 32 + lg * 8];
                acc[nt] = __builtin_amdgcn_mfma_f32_16x16x32_bf16(a5[ks], b, acc[nt], 0, 0, 0);
            }
        }
        #pragma unroll
        for (int nt = 0; nt < 8; ++nt) {
            float bias = b1s[nt * 16 + lr];
            #pragma unroll
            for (int r = 0; r < 4; ++r) {
                float h = acc[nt][r] + bias;
                s_h1[(w * 16 + lg * 4 + r) * 136 + nt * 16 + lr] = f2bf(h > 0.f ? h : 0.f);
            }
        }
    }
    __syncthreads();

    // ---- L2: per etype, g_t = h1 @ W2t ----
    short8 a2[4];
    #pragma unroll
    for (int ks = 0; ks < 4; ++ks)
        a2[ks] = *(const short8*)&s_h1[(w * 16 + lr) * 136 + ks * 32 + lg * 8];
    for (int t = gt0; t < gt1; ++t) {
        f32x4 acc2[4];
        #pragma unroll
        for (int nt = 0; nt < 4; ++nt) acc2[nt] = (f32x4){0.f, 0.f, 0.f, 0.f};
        #pragma unroll
        for (int nt = 0; nt < 4; ++nt) {
            #pragma unroll
            for (int ks = 0; ks < 4; ++ks) {
                short8 b = *(const short8*)&w2t[((size_t)t * OUT_DIM + nt * 16 + lr) * HID_DIM + ks * 32 + lg * 8];
                acc2[nt] = __builtin_amdgcn_mfma_f32_16x16x32_bf16(a2[ks], b, acc2[nt], 0, 0, 0);
            }
        }
        __syncthreads();          // prev s_out consumers done
        #pragma unroll
        for (int nt = 0; nt < 4; ++nt)
            #pragma unroll
            for (int r = 0; r < 4; ++r)
                s_out[(w * 16 + lg * 4 + r) * 72 + nt * 16 + lr] = f2bf(acc2[nt][r]);
        __syncthreads();
        size_t pb = (size_t)(t - gt0) * N_NODES;
        #pragma unroll
        for (int j = 0; j < 4; ++j) {
            int flat = j * 256 + tid;
            int rrow = flat >> 4, c4 = (flat & 15) * 4;
            int n = base + rrow;
            if (n < N_NODES)
                *(ushort4*)&g[(pb + n) * OUT_DIM + c4] = *(const ushort4*)&s_out[rrow * 72 + c4];
        }
    }
}

// ---------------- layer-2 gather: wave per node, etype range, h2 bf16 ----------------
__global__ __launch_bounds__(256) void k_gather2f(const int* __restrict__ bucket,
                                                  const int* __restrict__ ovfn_g,
                                                  const long long* __restrict__ ovf,
                                                  const u16* __restrict__ g,
                                                  u16* __restrict__ h2,
                                                  int t0, int tcnt, int add) {
    int n = blockIdx.x * 4 + (threadIdx.x >> 6);
    int lane = threadIdx.x & 63;
    float acc = 0.f;
    for (int tc = 0; tc < tcnt; ++tc) {
        int row = (t0 + tc) * N_NODES + n;
        const int* brow = bucket + (size_t)row * ROWW;
        int bval = (lane < ROWW) ? brow[lane] : 0;
        int c = __shfl(bval, 0);
        int kmax = c < CAP ? c : CAP;
        const u16* gp = g + (size_t)tc * N_NODES * OUT_DIM;
        float s = bf2f(gp[(size_t)n * OUT_DIM + lane]);   // self
        float s0 = 0.f, s1 = 0.f, s2 = 0.f, s3 = 0.f;
        int k = 1;
        for (; k + 3 <= kmax; k += 4) {
            int p0 = __shfl(bval, k);
            int p1 = __shfl(bval, k + 1);
            int p2 = __shfl(bval, k + 2);
            int p3 = __shfl(bval, k + 3);
            s0 += bf2f(gp[(size_t)p0 * OUT_DIM + lane]);
            s1 += bf2f(gp[(size_t)p1 * OUT_DIM + lane]);
            s2 += bf2f(gp[(size_t)p2 * OUT_DIM + lane]);
            s3 += bf2f(gp[(size_t)p3 * OUT_DIM + lane]);
        }
        for (; k <= kmax; ++k) {
            int p0 = __shfl(bval, k);
            s0 += bf2f(gp[(size_t)p0 * OUT_DIM + lane]);
        }
        s += (s0 + s1) + (s2 + s3);
        if (c > CAP) {                                // ~2 rows in 500k
            int nov = *ovfn_g; if (nov > OVF_ENTRIES) nov = OVF_ENTRIES;
            for (int i = 0; i < nov; ++i) {
                long long v = ovf[i];
                if ((int)(v >> 32) == row)
                    s += bf2f(gp[(size_t)(v & 0xffffffffLL) * OUT_DIM + lane]);
            }
        }
        acc += s / (float)(c + 1);
    }
    size_t oi = (size_t)n * OUT_DIM + lane;
    h2[oi] = f2bf(add ? bf2f(h2[oi]) + acc : acc);
}

// ---------------- pooling ----------------
__global__ __launch_bounds__(256) void k_pool(const u16* __restrict__ h2,
                                              const int* __restrict__ gids,
                                              const float* __restrict__ b2,
                                              float* __restrict__ out) {
    __shared__ float red[4][OUT_DIM];
    int gid = blockIdx.x;
    int lo = 0, hi = N_NODES;
    while (lo < hi) { int mid = (lo + hi) >> 1; if (gids[mid] < gid) lo = mid + 1; else hi = mid; }
    int start = lo;
    hi = N_NODES;
    while (lo < hi) { int mid = (lo + hi) >> 1; if (gids[mid] < gid + 1) lo = mid + 1; else hi = mid; }
    int end = lo;
    int count = end - start;
    int r = threadIdx.x >> 6, j = threadIdx.x & 63;
    float acc = 0.f;
    for (int n = start + r; n < end; n += 4)
        acc += bf2f(h2[(size_t)n * OUT_DIM + j]);
    red[r][j] = acc;
    __syncthreads();
    if (r == 0) {
        float total = red[0][j] + red[1][j] + red[2][j] + red[3][j];
        float b = 0.f;
        #pragma unroll
        for (int t = 0; t < N_ETYPES; ++t) b += b2[t * OUT_DIM + j];
        float c = (float)count;
        out[gid * OUT_DIM + j] = (total + c * b) / fmaxf(c, 1.0f);
    }
}

extern "C" void kernel_launch(void* const* d_in, const int* in_sizes, int n_in,
                              void* d_out, int out_size, void* d_ws, size_t ws_size,
                              hipStream_t stream) {
    const float* x    = (const float*)d_in[0];
    const int*   edges= (const int*)d_in[1];
    const int*   gids = (const int*)d_in[2];
    const float* W1   = (const float*)d_in[3];
    const float* b1   = (const float*)d_in[4];
    const float* W2   = (const float*)d_in[5];
    const float* b2   = (const float*)d_in[6];
    float* out = (float*)d_out;

    // word-offset workspace layout; total 32,447,264 words = 129.79 MB
    int*       bucket = (int*)d_ws;                         // 12,000,000 (500k x 24)
    int*       ovfn   = bucket + 12000000;                  // 1 (pad to 12,000,016)
    long long* ovf    = (long long*)(bucket + 12000016);    // 16,384 words
    u16*       xb     = (u16*)(bucket + 12016400);          // 1,600,000 words
    u16*       w1t    = (u16*)(bucket + 13616400);          // 10,240 words
    u16*       w2t    = (u16*)(bucket + 13626640);          // 20,480 words
    float*     b1s    = (float*)(bucket + 13647120);        // 128 (pad to 13,647,264)
    u16*       acat   = (u16*)(bucket + 13647264);          // 6,000,000 words ([n][120])
    u16*       g      = (u16*)(bucket + 19647264);          // 3 planes: 9,600,000 words
    u16*       h2     = (u16*)(bucket + 29247264);          // 3,200,000 words

    hipMemsetAsync(bucket, 0, 12000016ULL * 4, stream);     // cnts + ovfn

    k_prep<<<80, 256, 0, stream>>>(W1, W2, b1, w1t, w2t, b1s);
    k_xb<<<(N_NODES * 32 + 255) / 256, 256, 0, stream>>>(x, xb);
    k_fill<<<dim3((N_EDGES + 255) / 256, N_ETYPES), 256, 0, stream>>>(edges, bucket, ovfn, ovf);

    k_gather1<<<dim3(N_NODES / 8, N_ETYPES), 256, 0, stream>>>(bucket, ovfn, ovf, xb, acat);

    int nblk = (N_NODES + 63) / 64;
    // two-pass etype split (3 + 2 g planes) -- fits 129.79 MB workspace always
    k_gemm12<<<nblk, 256, 0, stream>>>(acat, w1t, w2t, b1s, g, 0, 3);
    k_gather2f<<<N_NODES / 4, 256, 0, stream>>>(bucket, ovfn, ovf, g, h2, 0, 3, 0);
    k_gemm12<<<nblk, 256, 0, stream>>>(acat, w1t, w2t, b1s, g, 3, 5);
    k_gather2f<<<N_NODES / 4, 256, 0, stream>>>(bucket, ovfn, ovf, g, h2, 3, 2, 1);

    k_pool<<<NUM_GRAPHS, 256, 0, stream>>>(h2, gids, b2, out);
}

// Round 7
// 580.292 us; speedup vs baseline: 5.4112x; 1.0908x over previous
//
#include <hip/hip_runtime.h>

#define N_NODES 100000
#define N_EDGES 800000
#define N_ETYPES 5
#define NUM_GRAPHS 64
#define IN_DIM 23
#define HID_DIM 128
#define OUT_DIM 64
#define N_KEYS (N_NODES * N_ETYPES)      // 500,000  (key = dst*5 + t)
#define KPB 2048                         // keys per bin
#define NBINS ((N_KEYS + KPB - 1) / KPB) // 245
#define BIN_CAP 18432                    // Poisson(16384) + 16 sigma
#define CHUNK 8192                       // edges per k_bin block
#define TOT_EDGES (N_EDGES * N_ETYPES)   // 4,000,000

typedef unsigned short u16;
using short8 = __attribute__((ext_vector_type(8))) short;
using f32x4  = __attribute__((ext_vector_type(4))) float;

__device__ __forceinline__ float bf2f(u16 v) {
    union { unsigned u; float f; } x; x.u = ((unsigned)v) << 16; return x.f;
}
__device__ __forceinline__ u16 f2bf(float f) {
    union { float f; unsigned u; } x; x.f = f;
    unsigned r = x.u + 0x7fff + ((x.u >> 16) & 1);   // RNE
    return (u16)(r >> 16);
}

// ---------------- prep: W1t/W2t/b1s (bf16, transposed, zero-padded) ----------------
__global__ __launch_bounds__(256) void k_prep(const float* __restrict__ W1,
                                              const float* __restrict__ W2,
                                              const float* __restrict__ b1,
                                              u16* __restrict__ w1t,
                                              u16* __restrict__ w2t,
                                              float* __restrict__ b1s) {
    int stride = gridDim.x * 256;
    int g0 = blockIdx.x * 256 + threadIdx.x;
    for (int i = g0; i < HID_DIM * 160; i += stride) {       // w1t[hid][k], k=t*32+f
        int hid = i / 160, k = i - hid * 160;
        int t = k >> 5, f = k & 31;
        w1t[i] = (f < IN_DIM) ? f2bf(W1[((size_t)t * IN_DIM + f) * HID_DIM + hid]) : (u16)0;
    }
    for (int i = g0; i < N_ETYPES * OUT_DIM * HID_DIM; i += stride) { // w2t[t][out][k]
        int t = i >> 13, r = i & 8191;
        int out = r >> 7, k = r & 127;
        w2t[i] = f2bf(W2[((size_t)t * HID_DIM + k) * OUT_DIM + out]);
    }
    for (int i = g0; i < HID_DIM; i += stride) {
        float s = 0.f;
        #pragma unroll
        for (int t = 0; t < N_ETYPES; ++t) s += b1[t * HID_DIM + i];
        b1s[i] = s;
    }
}

// ---------------- xb: x -> bf16, padded to 32 cols (64B rows) ----------------
__global__ __launch_bounds__(256) void k_xb(const float* __restrict__ x,
                                            u16* __restrict__ xb) {
    int i = blockIdx.x * 256 + threadIdx.x;
    if (i >= N_NODES * 32) return;
    int n = i >> 5, f = i & 31;
    xb[i] = (f < IN_DIM) ? f2bf(x[(size_t)n * IN_DIM + f]) : (u16)0;
}

// ---------------- pass A: bin edges by key>>11, LDS-aggregated (120k global atomics) -------
__global__ __launch_bounds__(256) void k_bin(const int* __restrict__ edges,
                                             int* __restrict__ bin_cnt,
                                             int* __restrict__ binned) {
    __shared__ int s_key[CHUNK];      // 32 KB
    __shared__ int s_hist[NBINS];
    __shared__ int s_base[NBINS];
    int tid = threadIdx.x;
    int g0 = blockIdx.x * CHUNK;
    int nch = TOT_EDGES - g0; if (nch > CHUNK) nch = CHUNK;
    for (int i = tid; i < NBINS; i += 256) s_hist[i] = 0;
    __syncthreads();
    // sweep 1: read dst, histogram bins, stash keys
    for (int i = tid; i < nch; i += 256) {
        int gi = g0 + i;
        int t = (unsigned)gi / (unsigned)N_EDGES;          // const divisor -> magic mul
        int e = gi - t * N_EDGES;
        int dst = edges[((size_t)t * 2 + 1) * N_EDGES + e];
        int key = dst * N_ETYPES + t;
        s_key[i] = key;
        atomicAdd(&s_hist[key >> 11], 1);
    }
    __syncthreads();
    // reserve: one global atomic per non-empty (block, bin)
    for (int i = tid; i < NBINS; i += 256) {
        int h = s_hist[i];
        s_base[i] = h ? atomicAdd(&bin_cnt[i], h) : 0;
    }
    __syncthreads();
    // sweep 2: read src, place entries
    for (int i = tid; i < nch; i += 256) {
        int gi = g0 + i;
        int t = (unsigned)gi / (unsigned)N_EDGES;
        int e = gi - t * N_EDGES;
        int src = edges[((size_t)t * 2 + 0) * N_EDGES + e];
        int key = s_key[i];
        int bin = key >> 11;
        int pos = atomicAdd(&s_base[bin], 1);   // s_base now = running offset
        if (pos < BIN_CAP)
            binned[(size_t)bin * BIN_CAP + pos] = ((key & 2047) << 17) | src;
    }
}

// ---------------- pass B: per-bin counting sort -> rowptr + CSR ----------------
__global__ __launch_bounds__(256) void k_csr(const int* __restrict__ bin_cnt,
                                             const int* __restrict__ binned,
                                             int* __restrict__ rowptr,
                                             int* __restrict__ csr) {
    __shared__ int s_cnt[KPB];        // 8 KB
    __shared__ int s_ofs[KPB];        // 8 KB
    __shared__ int s_red[256];
    int tid = threadIdx.x;
    int b = blockIdx.x;
    // csr_base = sum bin_cnt[0..b)
    int ps = 0;
    for (int i = tid; i < b; i += 256) ps += bin_cnt[i];
    s_red[tid] = ps;
    __syncthreads();
    for (int s = 128; s > 0; s >>= 1) {
        if (tid < s) s_red[tid] += s_red[tid + s];
        __syncthreads();
    }
    int csr_base = s_red[0];
    __syncthreads();
    int cnt_b = bin_cnt[b];
    if (cnt_b > BIN_CAP) cnt_b = BIN_CAP;
    int key0 = b * KPB;
    int keys_in = N_KEYS - key0; if (keys_in > KPB) keys_in = KPB;
    for (int i = tid; i < KPB; i += 256) s_cnt[i] = 0;
    __syncthreads();
    const int* ep = binned + (size_t)b * BIN_CAP;
    for (int i = tid; i < cnt_b; i += 256)
        atomicAdd(&s_cnt[ep[i] >> 17], 1);
    __syncthreads();
    // exclusive scan over 2048 counters: 8/thread serial + block Hillis-Steele
    int loc[8]; int base_t = 0;
    #pragma unroll
    for (int q = 0; q < 8; ++q) { loc[q] = base_t; base_t += s_cnt[tid * 8 + q]; }
    s_red[tid] = base_t;
    __syncthreads();
    for (int s = 1; s < 256; s <<= 1) {
        int add = (tid >= s) ? s_red[tid - s] : 0;
        __syncthreads();
        s_red[tid] += add;
        __syncthreads();
    }
    int excl = (tid == 0) ? 0 : s_red[tid - 1];
    #pragma unroll
    for (int q = 0; q < 8; ++q) {
        int k = tid * 8 + q;
        int o = excl + loc[q];
        s_ofs[k] = o;
        if (k < keys_in) rowptr[key0 + k] = csr_base + o;
    }
    if (b == NBINS - 1 && tid == 0) rowptr[N_KEYS] = csr_base + cnt_b;
    __syncthreads();
    // scatter into CSR (writes land in a 64KB L2-hot window)
    for (int i = tid; i < cnt_b; i += 256) {
        int entry = ep[i];
        int pos = atomicAdd(&s_ofs[entry >> 17], 1);
        csr[csr_base + pos] = entry & 0x1FFFF;
    }
}

// ---------------- layer-1 gather: half-wave per (node,etype) -> acat bf16 [n][120] --------
__global__ __launch_bounds__(256) void k_gather1(const int* __restrict__ rowptr,
                                                 const int* __restrict__ csr,
                                                 const u16* __restrict__ xb,
                                                 u16* __restrict__ acat) {
    int tid = threadIdx.x;
    int n = blockIdx.x * 8 + (tid >> 5);
    int f = tid & 31;
    int t = blockIdx.y;
    int lanebase = tid & 32;
    int key = n * N_ETYPES + t;
    int rp0 = rowptr[key];
    int deg = rowptr[key + 1] - rp0;
    int stage = csr[rp0 + f];                 // csr padded by 64 words
    int kmax = deg < 32 ? deg : 32;
    float acc = bf2f(xb[(size_t)n * 32 + f]); // gcn self
    float a0 = 0.f, a1 = 0.f, a2 = 0.f, a3 = 0.f;
    int k = 0;
    for (; k + 3 < kmax; k += 4) {
        int s0 = __shfl(stage, lanebase + k);
        int s1 = __shfl(stage, lanebase + k + 1);
        int s2 = __shfl(stage, lanebase + k + 2);
        int s3 = __shfl(stage, lanebase + k + 3);
        a0 += bf2f(xb[(size_t)s0 * 32 + f]);
        a1 += bf2f(xb[(size_t)s1 * 32 + f]);
        a2 += bf2f(xb[(size_t)s2 * 32 + f]);
        a3 += bf2f(xb[(size_t)s3 * 32 + f]);
    }
    for (; k < kmax; ++k) {
        int s0 = __shfl(stage, lanebase + k);
        a0 += bf2f(xb[(size_t)s0 * 32 + f]);
    }
    for (; k < deg; ++k) {                    // deg>32: ~never (Poisson(8)); uniform load
        int s0 = csr[rp0 + k];
        a0 += bf2f(xb[(size_t)s0 * 32 + f]);
    }
    acc += (a0 + a1) + (a2 + a3);
    if (f < 24) acat[(size_t)n * 120 + t * 24 + f] = f2bf(acc / (float)(deg + 1));
}

// ---------------- fused GEMM chain: acat -> MFMA L1+relu (LDS) -> MFMA L2 -> g -------------
__global__ __launch_bounds__(256) void k_gemm12(const u16* __restrict__ acat,
                                                const u16* __restrict__ w1t,
                                                const u16* __restrict__ w2t,
                                                const float* __restrict__ b1s,
                                                u16* __restrict__ g,
                                                int gt0, int gt1) {
    __shared__ u16 s_a[64 * 168];     // [64][160+8]  21504 B  (reused as s_out)
    __shared__ u16 s_h1[64 * 136];    // [64][128+8]  17408 B
    u16* s_out = s_a;                 // dead after A-frags are in registers
    int tid = threadIdx.x;
    int base = blockIdx.x * 64;

    // stage acat tile: expand [120] packed -> [160] zero-padded (coalesced ushort4)
    for (int i = tid; i < 64 * 40; i += 256) {
        int r = i / 40, col4 = i - r * 40;
        int t = col4 >> 3, q4 = col4 & 7;
        ushort4 v = {0, 0, 0, 0};
        if (q4 < 6 && base + r < N_NODES)
            v = *(const ushort4*)&acat[(size_t)(base + r) * 120 + t * 24 + q4 * 4];
        *(ushort4*)&s_a[r * 168 + t * 32 + q4 * 4] = v;
    }
    __syncthreads();

    int l = tid & 63, w = tid >> 6;
    int lr = l & 15, lg = l >> 4;

    // ---- L1: h1 = relu(s_a @ W1t + b1s) ----
    short8 a5[5];
    #pragma unroll
    for (int ks = 0; ks < 5; ++ks)
        a5[ks] = *(const short8*)&s_a[(w * 16 + lr) * 168 + ks * 32 + lg * 8];
    {
        f32x4 acc[8];
        #pragma unroll
        for (int nt = 0; nt < 8; ++nt) acc[nt] = (f32x4){0.f, 0.f, 0.f, 0.f};
        #pragma unroll
        for (int nt = 0; nt < 8; ++nt) {
            #pragma unroll
            for (int ks = 0; ks < 5; ++ks) {
                short8 b = *(const short8*)&w1t[(nt * 16 + lr) * 160 + ks * 32 + lg * 8];
                acc[nt] = __builtin_amdgcn_mfma_f32_16x16x32_bf16(a5[ks], b, acc[nt], 0, 0, 0);
            }
        }
        #pragma unroll
        for (int nt = 0; nt < 8; ++nt) {
            float bias = b1s[nt * 16 + lr];
            #pragma unroll
            for (int r = 0; r < 4; ++r) {
                float h = acc[nt][r] + bias;
                s_h1[(w * 16 + lg * 4 + r) * 136 + nt * 16 + lr] = f2bf(h > 0.f ? h : 0.f);
            }
        }
    }
    __syncthreads();

    // ---- L2: per etype, g_t = h1 @ W2t ----
    short8 a2[4];
    #pragma unroll
    for (int ks = 0; ks < 4; ++ks)
        a2[ks] = *(const short8*)&s_h1[(w * 16 + lr) * 136 + ks * 32 + lg * 8];
    for (int t = gt0; t < gt1; ++t) {
        f32x4 acc2[4];
        #pragma unroll
        for (int nt = 0; nt < 4; ++nt) acc2[nt] = (f32x4){0.f, 0.f, 0.f, 0.f};
        #pragma unroll
        for (int nt = 0; nt < 4; ++nt) {
            #pragma unroll
            for (int ks = 0; ks < 4; ++ks) {
                short8 b = *(const short8*)&w2t[((size_t)t * OUT_DIM + nt * 16 + lr) * HID_DIM + ks * 32 + lg * 8];
                acc2[nt] = __builtin_amdgcn_mfma_f32_16x16x32_bf16(a2[ks], b, acc2[nt], 0, 0, 0);
            }
        }
        __syncthreads();          // prev s_out consumers done
        #pragma unroll
        for (int nt = 0; nt < 4; ++nt)
            #pragma unroll
            for (int r = 0; r < 4; ++r)
                s_out[(w * 16 + lg * 4 + r) * 72 + nt * 16 + lr] = f2bf(acc2[nt][r]);
        __syncthreads();
        size_t pb = (size_t)(t - gt0) * N_NODES;
        #pragma unroll
        for (int j = 0; j < 4; ++j) {
            int flat = j * 256 + tid;
            int rrow = flat >> 4, c4 = (flat & 15) * 4;
            int n = base + rrow;
            if (n < N_NODES)
                *(ushort4*)&g[(pb + n) * OUT_DIM + c4] = *(const ushort4*)&s_out[rrow * 72 + c4];
        }
    }
}

// ---------------- layer-2 gather: wave per node, etype range, h2 bf16 ----------------
__global__ __launch_bounds__(256) void k_gather2f(const int* __restrict__ rowptr,
                                                  const int* __restrict__ csr,
                                                  const u16* __restrict__ g,
                                                  u16* __restrict__ h2,
                                                  int t0, int tcnt, int add) {
    int n = blockIdx.x * 4 + (threadIdx.x >> 6);
    int lane = threadIdx.x & 63;
    int kb = n * N_ETYPES + t0;
    float acc = 0.f;
    for (int tc = 0; tc < tcnt; ++tc) {
        int rp0 = rowptr[kb + tc];
        int deg = rowptr[kb + tc + 1] - rp0;
        int stage = csr[rp0 + lane];           // csr padded by 64 words
        int kmax = deg < 64 ? deg : 64;
        const u16* gp = g + (size_t)tc * N_NODES * OUT_DIM;
        float s = bf2f(gp[(size_t)n * OUT_DIM + lane]);   // self
        float s0 = 0.f, s1 = 0.f, s2 = 0.f, s3 = 0.f;
        int k = 0;
        for (; k + 3 < kmax; k += 4) {
            int p0 = __shfl(stage, k);
            int p1 = __shfl(stage, k + 1);
            int p2 = __shfl(stage, k + 2);
            int p3 = __shfl(stage, k + 3);
            s0 += bf2f(gp[(size_t)p0 * OUT_DIM + lane]);
            s1 += bf2f(gp[(size_t)p1 * OUT_DIM + lane]);
            s2 += bf2f(gp[(size_t)p2 * OUT_DIM + lane]);
            s3 += bf2f(gp[(size_t)p3 * OUT_DIM + lane]);
        }
        for (; k < kmax; ++k) {
            int p0 = __shfl(stage, k);
            s0 += bf2f(gp[(size_t)p0 * OUT_DIM + lane]);
        }
        for (; k < deg; ++k) {                 // deg>64: ~never; uniform broadcast load
            int p0 = csr[rp0 + k];
            s0 += bf2f(gp[(size_t)p0 * OUT_DIM + lane]);
        }
        s += (s0 + s1) + (s2 + s3);
        acc += s / (float)(deg + 1);
    }
    size_t oi = (size_t)n * OUT_DIM + lane;
    h2[oi] = f2bf(add ? bf2f(h2[oi]) + acc : acc);
}

// ---------------- pooling ----------------
__global__ __launch_bounds__(256) void k_pool(const u16* __restrict__ h2,
                                              const int* __restrict__ gids,
                                              const float* __restrict__ b2,
                                              float* __restrict__ out) {
    __shared__ float red[4][OUT_DIM];
    int gid = blockIdx.x;
    int lo = 0, hi = N_NODES;
    while (lo < hi) { int mid = (lo + hi) >> 1; if (gids[mid] < gid) lo = mid + 1; else hi = mid; }
    int start = lo;
    hi = N_NODES;
    while (lo < hi) { int mid = (lo + hi) >> 1; if (gids[mid] < gid + 1) lo = mid + 1; else hi = mid; }
    int end = lo;
    int count = end - start;
    int r = threadIdx.x >> 6, j = threadIdx.x & 63;
    float acc = 0.f;
    for (int n = start + r; n < end; n += 4)
        acc += bf2f(h2[(size_t)n * OUT_DIM + j]);
    red[r][j] = acc;
    __syncthreads();
    if (r == 0) {
        float total = red[0][j] + red[1][j] + red[2][j] + red[3][j];
        float b = 0.f;
        #pragma unroll
        for (int t = 0; t < N_ETYPES; ++t) b += b2[t * OUT_DIM + j];
        float c = (float)count;
        out[gid * OUT_DIM + j] = (total + c * b) / fmaxf(c, 1.0f);
    }
}

extern "C" void kernel_launch(void* const* d_in, const int* in_sizes, int n_in,
                              void* d_out, int out_size, void* d_ws, size_t ws_size,
                              hipStream_t stream) {
    const float* x    = (const float*)d_in[0];
    const int*   edges= (const int*)d_in[1];
    const int*   gids = (const int*)d_in[2];
    const float* W1   = (const float*)d_in[3];
    const float* b1   = (const float*)d_in[4];
    const float* W2   = (const float*)d_in[5];
    const float* b2   = (const float*)d_in[6];
    float* out = (float*)d_out;

    // word-offset workspace layout; total 29,447,040 words = 117.8 MB
    int*   bin_cnt = (int*)d_ws;                          // 256
    int*   rowptr  = bin_cnt + 256;                       // 500,001 -> pad 500,016
    int*   csr     = bin_cnt + 500272;                    // 4,000,064 -> pad 4,000,080
    int*   binned  = bin_cnt + 4500352;                   // 245*18432 = 4,515,840
    u16*   xb      = (u16*)(bin_cnt + 9016192);           // 1,600,000 words
    u16*   w1t     = (u16*)(bin_cnt + 10616192);          // 10,240 words
    u16*   w2t     = (u16*)(bin_cnt + 10626432);          // 20,480 words
    float* b1s     = (float*)(bin_cnt + 10646912);        // 128 words
    u16*   acat    = (u16*)(bin_cnt + 10647040);          // 6,000,000 words ([n][120])
    u16*   g       = (u16*)(bin_cnt + 16647040);          // 3 planes: 9,600,000 words
    u16*   h2      = (u16*)(bin_cnt + 26247040);          // 3,200,000 words

    hipMemsetAsync(bin_cnt, 0, 256 * sizeof(int), stream);

    k_prep<<<80, 256, 0, stream>>>(W1, W2, b1, w1t, w2t, b1s);
    k_xb<<<(N_NODES * 32 + 255) / 256, 256, 0, stream>>>(x, xb);
    k_bin<<<(TOT_EDGES + CHUNK - 1) / CHUNK, 256, 0, stream>>>(edges, bin_cnt, binned);
    k_csr<<<NBINS, 256, 0, stream>>>(bin_cnt, binned, rowptr, csr);

    k_gather1<<<dim3(N_NODES / 8, N_ETYPES), 256, 0, stream>>>(rowptr, csr, xb, acat);

    int nblk = (N_NODES + 63) / 64;
    // two-pass etype split (3 + 2 g planes)
    k_gemm12<<<nblk, 256, 0, stream>>>(acat, w1t, w2t, b1s, g, 0, 3);
    k_gather2f<<<N_NODES / 4, 256, 0, stream>>>(rowptr, csr, g, h2, 0, 3, 0);
    k_gemm12<<<nblk, 256, 0, stream>>>(acat, w1t, w2t, b1s, g, 3, 5);
    k_gather2f<<<N_NODES / 4, 256, 0, stream>>>(rowptr, csr, g, h2, 3, 2, 1);

    k_pool<<<NUM_GRAPHS, 256, 0, stream>>>(h2, gids, b2, out);
}

// Round 8
// 521.386 us; speedup vs baseline: 6.0226x; 1.1130x over previous
//
#include <hip/hip_runtime.h>

#define N_NODES 100000
#define N_EDGES 800000
#define N_ETYPES 5
#define NUM_GRAPHS 64
#define IN_DIM 23
#define HID_DIM 128
#define OUT_DIM 64
#define N_KEYS (N_NODES * N_ETYPES)      // 500,000  (key = dst*5 + t)
#define KPB 2048                         // keys per bin
#define NBINS ((N_KEYS + KPB - 1) / KPB) // 245
#define BIN_CAP 18432                    // Poisson(16384) + 16 sigma
#define CHUNK 8192                       // edges per k_bin block
#define TOT_EDGES (N_EDGES * N_ETYPES)   // 4,000,000

typedef unsigned short u16;
using short8 = __attribute__((ext_vector_type(8))) short;
using f32x4  = __attribute__((ext_vector_type(4))) float;

__device__ __forceinline__ float bf2f(u16 v) {
    union { unsigned u; float f; } x; x.u = ((unsigned)v) << 16; return x.f;
}
__device__ __forceinline__ u16 f2bf(float f) {
    union { float f; unsigned u; } x; x.f = f;
    unsigned r = x.u + 0x7fff + ((x.u >> 16) & 1);   // RNE
    return (u16)(r >> 16);
}

// ---------------- prep: W1t/W2t/b1s (bf16, transposed, zero-padded) ----------------
__global__ __launch_bounds__(256) void k_prep(const float* __restrict__ W1,
                                              const float* __restrict__ W2,
                                              const float* __restrict__ b1,
                                              u16* __restrict__ w1t,
                                              u16* __restrict__ w2t,
                                              float* __restrict__ b1s) {
    int stride = gridDim.x * 256;
    int g0 = blockIdx.x * 256 + threadIdx.x;
    for (int i = g0; i < HID_DIM * 160; i += stride) {       // w1t[hid][k], k=t*32+f
        int hid = i / 160, k = i - hid * 160;
        int t = k >> 5, f = k & 31;
        w1t[i] = (f < IN_DIM) ? f2bf(W1[((size_t)t * IN_DIM + f) * HID_DIM + hid]) : (u16)0;
    }
    for (int i = g0; i < N_ETYPES * OUT_DIM * HID_DIM; i += stride) { // w2t[t][out][k]
        int t = i >> 13, r = i & 8191;
        int out = r >> 7, k = r & 127;
        w2t[i] = f2bf(W2[((size_t)t * HID_DIM + k) * OUT_DIM + out]);
    }
    for (int i = g0; i < HID_DIM; i += stride) {
        float s = 0.f;
        #pragma unroll
        for (int t = 0; t < N_ETYPES; ++t) s += b1[t * HID_DIM + i];
        b1s[i] = s;
    }
}

// ---------------- xb: x -> bf16, padded to 32 cols (64B rows) ----------------
__global__ __launch_bounds__(256) void k_xb(const float* __restrict__ x,
                                            u16* __restrict__ xb) {
    int i = blockIdx.x * 256 + threadIdx.x;
    if (i >= N_NODES * 32) return;
    int n = i >> 5, f = i & 31;
    xb[i] = (f < IN_DIM) ? f2bf(x[(size_t)n * IN_DIM + f]) : (u16)0;
}

// ---------------- pass A: bin edges by key>>11, per-wave LDS histograms ----------------
__global__ __launch_bounds__(256) void k_bin(const int* __restrict__ edges,
                                             int* __restrict__ bin_cnt,
                                             int* __restrict__ binned) {
    __shared__ int s_key[CHUNK];      // 32 KB
    __shared__ int s_hist[4][256];    // 4 KB (per-wave)
    __shared__ int s_base[4][256];    // 4 KB (per-wave running offsets)
    int tid = threadIdx.x;
    int w = tid >> 6;
    int g0 = blockIdx.x * CHUNK;
    int nch = TOT_EDGES - g0; if (nch > CHUNK) nch = CHUNK;
    for (int i = tid; i < 4 * 256; i += 256) ((int*)s_hist)[i] = 0;
    __syncthreads();
    // sweep 1: read dst, per-wave histogram, stash keys
    for (int i = tid; i < nch; i += 256) {
        int gi = g0 + i;
        int t = (unsigned)gi / (unsigned)N_EDGES;          // const divisor -> magic mul
        int e = gi - t * N_EDGES;
        int dst = edges[((size_t)t * 2 + 1) * N_EDGES + e];
        int key = dst * N_ETYPES + t;
        s_key[i] = key;
        atomicAdd(&s_hist[w][key >> 11], 1);
    }
    __syncthreads();
    // reserve: one global atomic per non-empty (block, bin); per-wave sub-bases
    for (int i = tid; i < NBINS; i += 256) {
        int h0 = s_hist[0][i], h1 = s_hist[1][i], h2 = s_hist[2][i], h3 = s_hist[3][i];
        int h = h0 + h1 + h2 + h3;
        int base = h ? atomicAdd(&bin_cnt[i], h) : 0;
        s_base[0][i] = base;
        s_base[1][i] = base + h0;
        s_base[2][i] = base + h0 + h1;
        s_base[3][i] = base + h0 + h1 + h2;
    }
    __syncthreads();
    // sweep 2: read src, place entries (same thread -> same edges as sweep 1)
    for (int i = tid; i < nch; i += 256) {
        int gi = g0 + i;
        int t = (unsigned)gi / (unsigned)N_EDGES;
        int e = gi - t * N_EDGES;
        int src = edges[((size_t)t * 2 + 0) * N_EDGES + e];
        int key = s_key[i];
        int bin = key >> 11;
        int pos = atomicAdd(&s_base[w][bin], 1);
        if (pos < BIN_CAP)
            binned[(size_t)bin * BIN_CAP + pos] = ((key & 2047) << 17) | src;
    }
}

// ---------------- pass B: per-bin counting sort -> rowptr + CSR ----------------
__global__ __launch_bounds__(256) void k_csr(const int* __restrict__ bin_cnt,
                                             const int* __restrict__ binned,
                                             int* __restrict__ rowptr,
                                             int* __restrict__ csr) {
    __shared__ int s_cnt[KPB];        // 8 KB
    __shared__ int s_ofs[KPB];        // 8 KB
    __shared__ int s_red[256];
    int tid = threadIdx.x;
    int b = blockIdx.x;
    // csr_base = sum bin_cnt[0..b)
    int ps = 0;
    for (int i = tid; i < b; i += 256) ps += bin_cnt[i];
    s_red[tid] = ps;
    __syncthreads();
    for (int s = 128; s > 0; s >>= 1) {
        if (tid < s) s_red[tid] += s_red[tid + s];
        __syncthreads();
    }
    int csr_base = s_red[0];
    __syncthreads();
    int cnt_b = bin_cnt[b];
    if (cnt_b > BIN_CAP) cnt_b = BIN_CAP;
    int key0 = b * KPB;
    int keys_in = N_KEYS - key0; if (keys_in > KPB) keys_in = KPB;
    for (int i = tid; i < KPB; i += 256) s_cnt[i] = 0;
    __syncthreads();
    const int* ep = binned + (size_t)b * BIN_CAP;
    for (int i = tid; i < cnt_b; i += 256)
        atomicAdd(&s_cnt[ep[i] >> 17], 1);
    __syncthreads();
    // exclusive scan over 2048 counters: 8/thread serial + block Hillis-Steele
    int loc[8]; int base_t = 0;
    #pragma unroll
    for (int q = 0; q < 8; ++q) { loc[q] = base_t; base_t += s_cnt[tid * 8 + q]; }
    s_red[tid] = base_t;
    __syncthreads();
    for (int s = 1; s < 256; s <<= 1) {
        int add = (tid >= s) ? s_red[tid - s] : 0;
        __syncthreads();
        s_red[tid] += add;
        __syncthreads();
    }
    int excl = (tid == 0) ? 0 : s_red[tid - 1];
    #pragma unroll
    for (int q = 0; q < 8; ++q) {
        int k = tid * 8 + q;
        int o = excl + loc[q];
        s_ofs[k] = o;
        if (k < keys_in) rowptr[key0 + k] = csr_base + o;
    }
    if (b == NBINS - 1 && tid == 0) rowptr[N_KEYS] = csr_base + cnt_b;
    __syncthreads();
    // scatter into CSR (writes land in a 64KB L2-hot window)
    for (int i = tid; i < cnt_b; i += 256) {
        int entry = ep[i];
        int pos = atomicAdd(&s_ofs[entry >> 17], 1);
        csr[csr_base + pos] = entry & 0x1FFFF;
    }
}

// ---------------- layer-1 gather: half-wave per (node,etype) -> acat bf16 [n][120] --------
__global__ __launch_bounds__(256) void k_gather1(const int* __restrict__ rowptr,
                                                 const int* __restrict__ csr,
                                                 const u16* __restrict__ xb,
                                                 u16* __restrict__ acat) {
    int tid = threadIdx.x;
    int n = blockIdx.x * 8 + (tid >> 5);
    int f = tid & 31;
    int t = blockIdx.y;
    int lanebase = tid & 32;
    int key = n * N_ETYPES + t;
    int rp0 = rowptr[key];
    int deg = rowptr[key + 1] - rp0;
    int stage = csr[rp0 + f];                 // csr padded by 64 words
    int kmax = deg < 32 ? deg : 32;
    float acc = bf2f(xb[(size_t)n * 32 + f]); // gcn self
    float a0 = 0.f, a1 = 0.f, a2 = 0.f, a3 = 0.f;
    int k = 0;
    for (; k + 3 < kmax; k += 4) {
        int s0 = __shfl(stage, lanebase + k);
        int s1 = __shfl(stage, lanebase + k + 1);
        int s2 = __shfl(stage, lanebase + k + 2);
        int s3 = __shfl(stage, lanebase + k + 3);
        a0 += bf2f(xb[(size_t)s0 * 32 + f]);
        a1 += bf2f(xb[(size_t)s1 * 32 + f]);
        a2 += bf2f(xb[(size_t)s2 * 32 + f]);
        a3 += bf2f(xb[(size_t)s3 * 32 + f]);
    }
    for (; k < kmax; ++k) {
        int s0 = __shfl(stage, lanebase + k);
        a0 += bf2f(xb[(size_t)s0 * 32 + f]);
    }
    for (; k < deg; ++k) {                    // deg>32: ~never (Poisson(8)); uniform load
        int s0 = csr[rp0 + k];
        a0 += bf2f(xb[(size_t)s0 * 32 + f]);
    }
    acc += (a0 + a1) + (a2 + a3);
    if (f < 24) acat[(size_t)n * 120 + t * 24 + f] = f2bf(acc / (float)(deg + 1));
}

// ---------------- fused GEMM chain: acat -> MFMA L1+relu (LDS) -> MFMA L2 -> g -------------
__global__ __launch_bounds__(256) void k_gemm12(const u16* __restrict__ acat,
                                                const u16* __restrict__ w1t,
                                                const u16* __restrict__ w2t,
                                                const float* __restrict__ b1s,
                                                u16* __restrict__ g,
                                                int gt0, int gt1) {
    __shared__ u16 s_a[64 * 168];     // [64][160+8]  21504 B  (reused as s_out)
    __shared__ u16 s_h1[64 * 136];    // [64][128+8]  17408 B
    u16* s_out = s_a;                 // dead after A-frags are in registers
    int tid = threadIdx.x;
    int base = blockIdx.x * 64;

    // stage acat tile: expand [120] packed -> [160] zero-padded (coalesced ushort4)
    for (int i = tid; i < 64 * 40; i += 256) {
        int r = i / 40, col4 = i - r * 40;
        int t = col4 >> 3, q4 = col4 & 7;
        ushort4 v = {0, 0, 0, 0};
        if (q4 < 6 && base + r < N_NODES)
            v = *(const ushort4*)&acat[(size_t)(base + r) * 120 + t * 24 + q4 * 4];
        *(ushort4*)&s_a[r * 168 + t * 32 + q4 * 4] = v;
    }
    __syncthreads();

    int l = tid & 63, w = tid >> 6;
    int lr = l & 15, lg = l >> 4;

    // ---- L1: h1 = relu(s_a @ W1t + b1s) ----
    short8 a5[5];
    #pragma unroll
    for (int ks = 0; ks < 5; ++ks)
        a5[ks] = *(const short8*)&s_a[(w * 16 + lr) * 168 + ks * 32 + lg * 8];
    {
        f32x4 acc[8];
        #pragma unroll
        for (int nt = 0; nt < 8; ++nt) acc[nt] = (f32x4){0.f, 0.f, 0.f, 0.f};
        #pragma unroll
        for (int nt = 0; nt < 8; ++nt) {
            #pragma unroll
            for (int ks = 0; ks < 5; ++ks) {
                short8 b = *(const short8*)&w1t[(nt * 16 + lr) * 160 + ks * 32 + lg * 8];
                acc[nt] = __builtin_amdgcn_mfma_f32_16x16x32_bf16(a5[ks], b, acc[nt], 0, 0, 0);
            }
        }
        #pragma unroll
        for (int nt = 0; nt < 8; ++nt) {
            float bias = b1s[nt * 16 + lr];
            #pragma unroll
            for (int r = 0; r < 4; ++r) {
                float h = acc[nt][r] + bias;
                s_h1[(w * 16 + lg * 4 + r) * 136 + nt * 16 + lr] = f2bf(h > 0.f ? h : 0.f);
            }
        }
    }
    __syncthreads();

    // ---- L2: per etype, g_t = h1 @ W2t ----
    short8 a2[4];
    #pragma unroll
    for (int ks = 0; ks < 4; ++ks)
        a2[ks] = *(const short8*)&s_h1[(w * 16 + lr) * 136 + ks * 32 + lg * 8];
    for (int t = gt0; t < gt1; ++t) {
        f32x4 acc2[4];
        #pragma unroll
        for (int nt = 0; nt < 4; ++nt) acc2[nt] = (f32x4){0.f, 0.f, 0.f, 0.f};
        #pragma unroll
        for (int nt = 0; nt < 4; ++nt) {
            #pragma unroll
            for (int ks = 0; ks < 4; ++ks) {
                short8 b = *(const short8*)&w2t[((size_t)t * OUT_DIM + nt * 16 + lr) * HID_DIM + ks * 32 + lg * 8];
                acc2[nt] = __builtin_amdgcn_mfma_f32_16x16x32_bf16(a2[ks], b, acc2[nt], 0, 0, 0);
            }
        }
        __syncthreads();          // prev s_out consumers done
        #pragma unroll
        for (int nt = 0; nt < 4; ++nt)
            #pragma unroll
            for (int r = 0; r < 4; ++r)
                s_out[(w * 16 + lg * 4 + r) * 72 + nt * 16 + lr] = f2bf(acc2[nt][r]);
        __syncthreads();
        size_t pb = (size_t)(t - gt0) * N_NODES;
        #pragma unroll
        for (int j = 0; j < 4; ++j) {
            int flat = j * 256 + tid;
            int rrow = flat >> 4, c4 = (flat & 15) * 4;
            int n = base + rrow;
            if (n < N_NODES)
                *(ushort4*)&g[(pb + n) * OUT_DIM + c4] = *(const ushort4*)&s_out[rrow * 72 + c4];
        }
    }
}

// ---------------- layer-2 gather: wave per node, etype range, h2 bf16 ----------------
__global__ __launch_bounds__(256) void k_gather2f(const int* __restrict__ rowptr,
                                                  const int* __restrict__ csr,
                                                  const u16* __restrict__ g,
                                                  u16* __restrict__ h2,
                                                  int t0, int tcnt, int add) {
    int n = blockIdx.x * 4 + (threadIdx.x >> 6);
    int lane = threadIdx.x & 63;
    int kb = n * N_ETYPES + t0;
    float acc = 0.f;
    for (int tc = 0; tc < tcnt; ++tc) {
        int rp0 = rowptr[kb + tc];
        int deg = rowptr[kb + tc + 1] - rp0;
        int stage = csr[rp0 + lane];           // csr padded by 64 words
        int kmax = deg < 64 ? deg : 64;
        const u16* gp = g + (size_t)tc * N_NODES * OUT_DIM;
        float s = bf2f(gp[(size_t)n * OUT_DIM + lane]);   // self
        float s0 = 0.f, s1 = 0.f, s2 = 0.f, s3 = 0.f;
        int k = 0;
        for (; k + 3 < kmax; k += 4) {
            int p0 = __shfl(stage, k);
            int p1 = __shfl(stage, k + 1);
            int p2 = __shfl(stage, k + 2);
            int p3 = __shfl(stage, k + 3);
            s0 += bf2f(gp[(size_t)p0 * OUT_DIM + lane]);
            s1 += bf2f(gp[(size_t)p1 * OUT_DIM + lane]);
            s2 += bf2f(gp[(size_t)p2 * OUT_DIM + lane]);
            s3 += bf2f(gp[(size_t)p3 * OUT_DIM + lane]);
        }
        for (; k < kmax; ++k) {
            int p0 = __shfl(stage, k);
            s0 += bf2f(gp[(size_t)p0 * OUT_DIM + lane]);
        }
        for (; k < deg; ++k) {                 // deg>64: ~never; uniform broadcast load
            int p0 = csr[rp0 + k];
            s0 += bf2f(gp[(size_t)p0 * OUT_DIM + lane]);
        }
        s += (s0 + s1) + (s2 + s3);
        acc += s / (float)(deg + 1);
    }
    size_t oi = (size_t)n * OUT_DIM + lane;
    h2[oi] = f2bf(add ? bf2f(h2[oi]) + acc : acc);
}

// ---------------- pooling stage 1: chunked partial sums (sorted gids -> few atomics) -------
__global__ __launch_bounds__(256) void k_pool1(const u16* __restrict__ h2,
                                               const int* __restrict__ gids,
                                               float* __restrict__ out_acc) {
    int w = threadIdx.x >> 6, lane = threadIdx.x & 63;
    int n0 = blockIdx.x * 256 + w * 64;
    int nend = n0 + 64; if (nend > N_NODES) nend = N_NODES;
    float acc = 0.f;
    int cur = -1;
    for (int n = n0; n < nend; ++n) {
        int gid = gids[n];
        if (gid != cur) {
            if (cur >= 0) atomicAdd(&out_acc[cur * OUT_DIM + lane], acc);
            acc = 0.f; cur = gid;
        }
        acc += bf2f(h2[(size_t)n * OUT_DIM + lane]);
    }
    if (cur >= 0) atomicAdd(&out_acc[cur * OUT_DIM + lane], acc);
}

// ---------------- pooling stage 2: divide by count, add bias ----------------
__global__ __launch_bounds__(64) void k_pool2(const float* __restrict__ out_acc,
                                              const int* __restrict__ gids,
                                              const float* __restrict__ b2,
                                              float* __restrict__ out) {
    int gid = blockIdx.x, j = threadIdx.x;
    int lo = 0, hi = N_NODES;
    while (lo < hi) { int mid = (lo + hi) >> 1; if (gids[mid] < gid) lo = mid + 1; else hi = mid; }
    int start = lo;
    hi = N_NODES;
    while (lo < hi) { int mid = (lo + hi) >> 1; if (gids[mid] < gid + 1) lo = mid + 1; else hi = mid; }
    int count = lo - start;
    float b = 0.f;
    #pragma unroll
    for (int t = 0; t < N_ETYPES; ++t) b += b2[t * OUT_DIM + j];
    float c = (float)count;
    out[gid * OUT_DIM + j] = (out_acc[gid * OUT_DIM + j] + c * b) / fmaxf(c, 1.0f);
}

extern "C" void kernel_launch(void* const* d_in, const int* in_sizes, int n_in,
                              void* d_out, int out_size, void* d_ws, size_t ws_size,
                              hipStream_t stream) {
    const float* x    = (const float*)d_in[0];
    const int*   edges= (const int*)d_in[1];
    const int*   gids = (const int*)d_in[2];
    const float* W1   = (const float*)d_in[3];
    const float* b1   = (const float*)d_in[4];
    const float* W2   = (const float*)d_in[5];
    const float* b2   = (const float*)d_in[6];
    float* out = (float*)d_out;

    // word-offset workspace layout; total 29,451,136 words = 117.8 MB
    int*   bin_cnt = (int*)d_ws;                          // 256
    int*   rowptr  = bin_cnt + 256;                       // 500,001 -> pad 500,016
    int*   csr     = bin_cnt + 500272;                    // 4,000,064 -> pad 4,000,080
    int*   binned  = bin_cnt + 4500352;                   // 245*18432 = 4,515,840
    u16*   xb      = (u16*)(bin_cnt + 9016192);           // 1,600,000 words
    u16*   w1t     = (u16*)(bin_cnt + 10616192);          // 10,240 words
    u16*   w2t     = (u16*)(bin_cnt + 10626432);          // 20,480 words
    float* b1s     = (float*)(bin_cnt + 10646912);        // 128 words
    u16*   acat    = (u16*)(bin_cnt + 10647040);          // 6,000,000 words ([n][120])
    u16*   g       = (u16*)(bin_cnt + 16647040);          // 3 planes: 9,600,000 words
    u16*   h2      = (u16*)(bin_cnt + 26247040);          // 3,200,000 words
    float* out_acc = (float*)(bin_cnt + 29447040);        // 4,096 words

    hipMemsetAsync(bin_cnt, 0, 256 * sizeof(int), stream);
    hipMemsetAsync(out_acc, 0, NUM_GRAPHS * OUT_DIM * sizeof(float), stream);

    k_prep<<<80, 256, 0, stream>>>(W1, W2, b1, w1t, w2t, b1s);
    k_xb<<<(N_NODES * 32 + 255) / 256, 256, 0, stream>>>(x, xb);
    k_bin<<<(TOT_EDGES + CHUNK - 1) / CHUNK, 256, 0, stream>>>(edges, bin_cnt, binned);
    k_csr<<<NBINS, 256, 0, stream>>>(bin_cnt, binned, rowptr, csr);

    k_gather1<<<dim3(N_NODES / 8, N_ETYPES), 256, 0, stream>>>(rowptr, csr, xb, acat);

    int nblk = (N_NODES + 63) / 64;
    // two-pass etype split (3 + 2 g planes)
    k_gemm12<<<nblk, 256, 0, stream>>>(acat, w1t, w2t, b1s, g, 0, 3);
    k_gather2f<<<N_NODES / 4, 256, 0, stream>>>(rowptr, csr, g, h2, 0, 3, 0);
    k_gemm12<<<nblk, 256, 0, stream>>>(acat, w1t, w2t, b1s, g, 3, 5);
    k_gather2f<<<N_NODES / 4, 256, 0, stream>>>(rowptr, csr, g, h2, 3, 2, 1);

    k_pool1<<<(N_NODES + 255) / 256, 256, 0, stream>>>(h2, gids, out_acc);
    k_pool2<<<NUM_GRAPHS, 64, 0, stream>>>(out_acc, gids, b2, out);
}

// Round 10
// 420.626 us; speedup vs baseline: 7.4653x; 1.2395x over previous
//
#include <hip/hip_runtime.h>

#define N_NODES 100000
#define N_EDGES 800000
#define N_ETYPES 5
#define NUM_GRAPHS 64
#define IN_DIM 23
#define HID_DIM 128
#define OUT_DIM 64
#define N_KEYS (N_NODES * N_ETYPES)      // 500,000  (key = dst*5 + t)
#define KPB 2048                         // keys per bin
#define NBINS ((N_KEYS + KPB - 1) / KPB) // 245
#define BIN_CAP 18432                    // Poisson(16384) + 16 sigma
#define CHUNK 8192                       // edges per k_bin block
#define TOT_EDGES (N_EDGES * N_ETYPES)   // 4,000,000

typedef unsigned short u16;
typedef unsigned int u32;
using short8 = __attribute__((ext_vector_type(8))) short;
using f32x4  = __attribute__((ext_vector_type(4))) float;

__device__ __forceinline__ float bf2f(u16 v) {
    union { unsigned u; float f; } x; x.u = ((unsigned)v) << 16; return x.f;
}
__device__ __forceinline__ float lo2f(u32 v) {
    union { unsigned u; float f; } x; x.u = v << 16; return x.f;
}
__device__ __forceinline__ float hi2f(u32 v) {
    union { unsigned u; float f; } x; x.u = v & 0xffff0000u; return x.f;
}
__device__ __forceinline__ u16 f2bf(float f) {
    union { float f; unsigned u; } x; x.f = f;
    unsigned r = x.u + 0x7fff + ((x.u >> 16) & 1);   // RNE
    return (u16)(r >> 16);
}

// ---------------- prep: W1t/W2t/b1s (bf16, transposed, zero-padded) ----------------
__global__ __launch_bounds__(256) void k_prep(const float* __restrict__ W1,
                                              const float* __restrict__ W2,
                                              const float* __restrict__ b1,
                                              u16* __restrict__ w1t,
                                              u16* __restrict__ w2t,
                                              float* __restrict__ b1s) {
    int stride = gridDim.x * 256;
    int g0 = blockIdx.x * 256 + threadIdx.x;
    for (int i = g0; i < HID_DIM * 160; i += stride) {       // w1t[hid][k], k=t*32+f
        int hid = i / 160, k = i - hid * 160;
        int t = k >> 5, f = k & 31;
        w1t[i] = (f < IN_DIM) ? f2bf(W1[((size_t)t * IN_DIM + f) * HID_DIM + hid]) : (u16)0;
    }
    for (int i = g0; i < N_ETYPES * OUT_DIM * HID_DIM; i += stride) { // w2t[t][out][k]
        int t = i >> 13, r = i & 8191;
        int out = r >> 7, k = r & 127;
        w2t[i] = f2bf(W2[((size_t)t * HID_DIM + k) * OUT_DIM + out]);
    }
    for (int i = g0; i < HID_DIM; i += stride) {
        float s = 0.f;
        #pragma unroll
        for (int t = 0; t < N_ETYPES; ++t) s += b1[t * HID_DIM + i];
        b1s[i] = s;
    }
}

// ---------------- xb: x -> bf16, padded to 32 cols (64B rows) ----------------
__global__ __launch_bounds__(256) void k_xb(const float* __restrict__ x,
                                            u16* __restrict__ xb) {
    int i = blockIdx.x * 256 + threadIdx.x;
    if (i >= N_NODES * 32) return;
    int n = i >> 5, f = i & 31;
    xb[i] = (f < IN_DIM) ? f2bf(x[(size_t)n * IN_DIM + f]) : (u16)0;
}

// ---------------- pass A: bin edges by key>>11, per-wave LDS histograms ----------------
__global__ __launch_bounds__(256) void k_bin(const int* __restrict__ edges,
                                             int* __restrict__ bin_cnt,
                                             int* __restrict__ binned) {
    __shared__ int s_key[CHUNK];      // 32 KB
    __shared__ int s_hist[4][256];    // 4 KB (per-wave)
    __shared__ int s_base[4][256];    // 4 KB (per-wave running offsets)
    int tid = threadIdx.x;
    int w = tid >> 6;
    int g0 = blockIdx.x * CHUNK;
    int nch = TOT_EDGES - g0; if (nch > CHUNK) nch = CHUNK;
    for (int i = tid; i < 4 * 256; i += 256) ((int*)s_hist)[i] = 0;
    __syncthreads();
    // sweep 1: read dst, per-wave histogram, stash keys
    for (int i = tid; i < nch; i += 256) {
        int gi = g0 + i;
        int t = (unsigned)gi / (unsigned)N_EDGES;          // const divisor -> magic mul
        int e = gi - t * N_EDGES;
        int dst = edges[((size_t)t * 2 + 1) * N_EDGES + e];
        int key = dst * N_ETYPES + t;
        s_key[i] = key;
        atomicAdd(&s_hist[w][key >> 11], 1);
    }
    __syncthreads();
    // reserve: one global atomic per non-empty (block, bin); per-wave sub-bases
    for (int i = tid; i < NBINS; i += 256) {
        int h0 = s_hist[0][i], h1 = s_hist[1][i], h2 = s_hist[2][i], h3 = s_hist[3][i];
        int h = h0 + h1 + h2 + h3;
        int base = h ? atomicAdd(&bin_cnt[i], h) : 0;
        s_base[0][i] = base;
        s_base[1][i] = base + h0;
        s_base[2][i] = base + h0 + h1;
        s_base[3][i] = base + h0 + h1 + h2;
    }
    __syncthreads();
    // sweep 2: read src, place entries (same thread -> same edges as sweep 1)
    for (int i = tid; i < nch; i += 256) {
        int gi = g0 + i;
        int t = (unsigned)gi / (unsigned)N_EDGES;
        int e = gi - t * N_EDGES;
        int src = edges[((size_t)t * 2 + 0) * N_EDGES + e];
        int key = s_key[i];
        int bin = key >> 11;
        int pos = atomicAdd(&s_base[w][bin], 1);
        if (pos < BIN_CAP)
            binned[(size_t)bin * BIN_CAP + pos] = ((key & 2047) << 17) | src;
    }
}

// ---------------- pass B: per-bin counting sort -> rowptr + CSR ----------------
__global__ __launch_bounds__(256) void k_csr(const int* __restrict__ bin_cnt,
                                             const int* __restrict__ binned,
                                             int* __restrict__ rowptr,
                                             int* __restrict__ csr) {
    __shared__ int s_cnt[KPB];        // 8 KB
    __shared__ int s_ofs[KPB];        // 8 KB
    __shared__ int s_red[256];
    int tid = threadIdx.x;
    int b = blockIdx.x;
    // csr_base = sum bin_cnt[0..b)
    int ps = 0;
    for (int i = tid; i < b; i += 256) ps += bin_cnt[i];
    s_red[tid] = ps;
    __syncthreads();
    for (int s = 128; s > 0; s >>= 1) {
        if (tid < s) s_red[tid] += s_red[tid + s];
        __syncthreads();
    }
    int csr_base = s_red[0];
    __syncthreads();
    int cnt_b = bin_cnt[b];
    if (cnt_b > BIN_CAP) cnt_b = BIN_CAP;
    int key0 = b * KPB;
    int keys_in = N_KEYS - key0; if (keys_in > KPB) keys_in = KPB;
    for (int i = tid; i < KPB; i += 256) s_cnt[i] = 0;
    __syncthreads();
    const int* ep = binned + (size_t)b * BIN_CAP;
    for (int i = tid; i < cnt_b; i += 256)
        atomicAdd(&s_cnt[ep[i] >> 17], 1);
    __syncthreads();
    // exclusive scan over 2048 counters: 8/thread serial + block Hillis-Steele
    int loc[8]; int base_t = 0;
    #pragma unroll
    for (int q = 0; q < 8; ++q) { loc[q] = base_t; base_t += s_cnt[tid * 8 + q]; }
    s_red[tid] = base_t;
    __syncthreads();
    for (int s = 1; s < 256; s <<= 1) {
        int add = (tid >= s) ? s_red[tid - s] : 0;
        __syncthreads();
        s_red[tid] += add;
        __syncthreads();
    }
    int excl = (tid == 0) ? 0 : s_red[tid - 1];
    #pragma unroll
    for (int q = 0; q < 8; ++q) {
        int k = tid * 8 + q;
        int o = excl + loc[q];
        s_ofs[k] = o;
        if (k < keys_in) rowptr[key0 + k] = csr_base + o;
    }
    if (b == NBINS - 1 && tid == 0) rowptr[N_KEYS] = csr_base + cnt_b;
    __syncthreads();
    // scatter into CSR (writes land in a 64KB L2-hot window)
    for (int i = tid; i < cnt_b; i += 256) {
        int entry = ep[i];
        int pos = atomicAdd(&s_ofs[entry >> 17], 1);
        csr[csr_base + pos] = entry & 0x1FFFF;
    }
}

// ------------ layer-1 gather: 16-lane group per (node,etype), u32-packed feats ------------
__global__ __launch_bounds__(256) void k_gather1(const int* __restrict__ rowptr,
                                                 const int* __restrict__ csr,
                                                 const u32* __restrict__ xb32,
                                                 u32* __restrict__ acat32) {
    int tid = threadIdx.x;
    int lane = tid & 15;
    int lanebase = tid & 48;                  // group base within the 64-lane wave
    int n = blockIdx.x * 16 + (tid >> 4);
    int t = blockIdx.y;
    int key = n * N_ETYPES + t;
    int rp0 = rowptr[key];
    int deg = rowptr[key + 1] - rp0;
    int stage = csr[rp0 + lane];              // 16 staged entries (csr padded)
    int kmax = deg < 16 ? deg : 16;
    u32 v = xb32[(size_t)n * 16 + lane];      // self; pad cols are zero
    float acc0 = lo2f(v), acc1 = hi2f(v);
    float a00 = 0.f, a01 = 0.f, a10 = 0.f, a11 = 0.f;
    int k = 0;
    for (; k + 1 < kmax; k += 2) {
        int s0 = __shfl(stage, lanebase + k);
        int s1 = __shfl(stage, lanebase + k + 1);
        u32 v0 = xb32[(size_t)s0 * 16 + lane];
        u32 v1 = xb32[(size_t)s1 * 16 + lane];
        a00 += lo2f(v0); a01 += hi2f(v0);
        a10 += lo2f(v1); a11 += hi2f(v1);
    }
    if (k < kmax) {
        int s0 = __shfl(stage, lanebase + k);
        u32 v0 = xb32[(size_t)s0 * 16 + lane];
        a00 += lo2f(v0); a01 += hi2f(v0);
        ++k;
    }
    for (; k < deg; ++k) {                    // deg>16: rare (P~0.004), uniform loads
        int s0 = csr[rp0 + k];
        u32 v0 = xb32[(size_t)s0 * 16 + lane];
        a00 += lo2f(v0); a01 += hi2f(v0);
    }
    acc0 += a00 + a10;
    acc1 += a01 + a11;
    float inv = 1.0f / (float)(deg + 1);
    if (lane < 12)
        acat32[(size_t)n * 60 + t * 12 + lane] =
            (u32)f2bf(acc0 * inv) | ((u32)f2bf(acc1 * inv) << 16);
}

// ---------------- fused GEMM chain: acat -> MFMA L1+relu (LDS) -> MFMA L2 -> g -------------
__global__ __launch_bounds__(256) void k_gemm12(const u16* __restrict__ acat,
                                                const u16* __restrict__ w1t,
                                                const u16* __restrict__ w2t,
                                                const float* __restrict__ b1s,
                                                u16* __restrict__ g,
                                                int gt0, int gt1) {
    __shared__ u16 s_a[64 * 168];     // [64][160+8]  21504 B  (reused as s_out)
    __shared__ u16 s_h1[64 * 136];    // [64][128+8]  17408 B
    u16* s_out = s_a;                 // dead after A-frags are in registers
    int tid = threadIdx.x;
    int base = blockIdx.x * 64;

    // stage acat tile: expand [120] packed -> [160] zero-padded (coalesced ushort4)
    for (int i = tid; i < 64 * 40; i += 256) {
        int r = i / 40, col4 = i - r * 40;
        int t = col4 >> 3, q4 = col4 & 7;
        ushort4 v = {0, 0, 0, 0};
        if (q4 < 6 && base + r < N_NODES)
            v = *(const ushort4*)&acat[(size_t)(base + r) * 120 + t * 24 + q4 * 4];
        *(ushort4*)&s_a[r * 168 + t * 32 + q4 * 4] = v;
    }
    __syncthreads();

    int l = tid & 63, w = tid >> 6;
    int lr = l & 15, lg = l >> 4;

    // ---- L1: h1 = relu(s_a @ W1t + b1s) ----
    short8 a5[5];
    #pragma unroll
    for (int ks = 0; ks < 5; ++ks)
        a5[ks] = *(const short8*)&s_a[(w * 16 + lr) * 168 + ks * 32 + lg * 8];
    {
        f32x4 acc[8];
        #pragma unroll
        for (int nt = 0; nt < 8; ++nt) acc[nt] = (f32x4){0.f, 0.f, 0.f, 0.f};
        #pragma unroll
        for (int nt = 0; nt < 8; ++nt) {
            #pragma unroll
            for (int ks = 0; ks < 5; ++ks) {
                short8 b = *(const short8*)&w1t[(nt * 16 + lr) * 160 + ks * 32 + lg * 8];
                acc[nt] = __builtin_amdgcn_mfma_f32_16x16x32_bf16(a5[ks], b, acc[nt], 0, 0, 0);
            }
        }
        #pragma unroll
        for (int nt = 0; nt < 8; ++nt) {
            float bias = b1s[nt * 16 + lr];
            #pragma unroll
            for (int r = 0; r < 4; ++r) {
                float h = acc[nt][r] + bias;
                s_h1[(w * 16 + lg * 4 + r) * 136 + nt * 16 + lr] = f2bf(h > 0.f ? h : 0.f);
            }
        }
    }
    __syncthreads();

    // ---- L2: per etype, g_t = h1 @ W2t ----
    short8 a2[4];
    #pragma unroll
    for (int ks = 0; ks < 4; ++ks)
        a2[ks] = *(const short8*)&s_h1[(w * 16 + lr) * 136 + ks * 32 + lg * 8];
    for (int t = gt0; t < gt1; ++t) {
        f32x4 acc2[4];
        #pragma unroll
        for (int nt = 0; nt < 4; ++nt) acc2[nt] = (f32x4){0.f, 0.f, 0.f, 0.f};
        #pragma unroll
        for (int nt = 0; nt < 4; ++nt) {
            #pragma unroll
            for (int ks = 0; ks < 4; ++ks) {
                short8 b = *(const short8*)&w2t[((size_t)t * OUT_DIM + nt * 16 + lr) * HID_DIM + ks * 32 + lg * 8];
                acc2[nt] = __builtin_amdgcn_mfma_f32_16x16x32_bf16(a2[ks], b, acc2[nt], 0, 0, 0);
            }
        }
        __syncthreads();          // prev s_out consumers done
        #pragma unroll
        for (int nt = 0; nt < 4; ++nt)
            #pragma unroll
            for (int r = 0; r < 4; ++r)
                s_out[(w * 16 + lg * 4 + r) * 72 + nt * 16 + lr] = f2bf(acc2[nt][r]);
        __syncthreads();
        size_t pb = (size_t)(t - gt0) * N_NODES;
        #pragma unroll
        for (int j = 0; j < 4; ++j) {
            int flat = j * 256 + tid;
            int rrow = flat >> 4, c4 = (flat & 15) * 4;
            int n = base + rrow;
            if (n < N_NODES)
                *(ushort4*)&g[(pb + n) * OUT_DIM + c4] = *(const ushort4*)&s_out[rrow * 72 + c4];
        }
    }
}

// ------------ layer-2 gather: 32-lane group per node, all etypes, u32-packed ------------
__global__ __launch_bounds__(256) void k_gather2(const int* __restrict__ rowptr,
                                                 const int* __restrict__ csr,
                                                 const u32* __restrict__ g32,
                                                 u32* __restrict__ h232) {
    int tid = threadIdx.x;
    int lane = tid & 31;
    int lanebase = tid & 32;                  // group base within the 64-lane wave
    int n = blockIdx.x * 8 + (tid >> 5);
    int kb = n * N_ETYPES;
    float acc0 = 0.f, acc1 = 0.f;
    for (int tc = 0; tc < N_ETYPES; ++tc) {
        int rp0 = rowptr[kb + tc];
        int deg = rowptr[kb + tc + 1] - rp0;
        int stage = csr[rp0 + lane];          // 32 staged entries
        int kmax = deg < 32 ? deg : 32;
        const u32* gp = g32 + (size_t)tc * N_NODES * 32;
        u32 v = gp[(size_t)n * 32 + lane];    // self
        float s0 = lo2f(v), s1 = hi2f(v), s2 = 0.f, s3 = 0.f;
        int k = 0;
        for (; k + 1 < kmax; k += 2) {
            int p0 = __shfl(stage, lanebase + k);
            int p1 = __shfl(stage, lanebase + k + 1);
            u32 v0 = gp[(size_t)p0 * 32 + lane];
            u32 v1 = gp[(size_t)p1 * 32 + lane];
            s0 += lo2f(v0); s1 += hi2f(v0);
            s2 += lo2f(v1); s3 += hi2f(v1);
        }
        if (k < kmax) {
            int p0 = __shfl(stage, lanebase + k);
            u32 v0 = gp[(size_t)p0 * 32 + lane];
            s0 += lo2f(v0); s1 += hi2f(v0);
            ++k;
        }
        for (; k < deg; ++k) {                // deg>32: ~never; uniform broadcast load
            int p0 = csr[rp0 + k];
            u32 v0 = gp[(size_t)p0 * 32 + lane];
            s0 += lo2f(v0); s1 += hi2f(v0);
        }
        float inv = 1.0f / (float)(deg + 1);
        acc0 += (s0 + s2) * inv;
        acc1 += (s1 + s3) * inv;
    }
    h232[(size_t)n * 32 + lane] = (u32)f2bf(acc0) | ((u32)f2bf(acc1) << 16);
}

// ---------------- pooling stage 1: chunked partial sums (sorted gids -> few atomics) -------
__global__ __launch_bounds__(256) void k_pool1(const u16* __restrict__ h2,
                                               const int* __restrict__ gids,
                                               float* __restrict__ out_acc) {
    int w = threadIdx.x >> 6, lane = threadIdx.x & 63;
    int n0 = blockIdx.x * 256 + w * 64;
    int nend = n0 + 64; if (nend > N_NODES) nend = N_NODES;
    float acc = 0.f;
    int cur = -1;
    for (int n = n0; n < nend; ++n) {
        int gid = gids[n];
        if (gid != cur) {
            if (cur >= 0) atomicAdd(&out_acc[cur * OUT_DIM + lane], acc);
            acc = 0.f; cur = gid;
        }
        acc += bf2f(h2[(size_t)n * OUT_DIM + lane]);
    }
    if (cur >= 0) atomicAdd(&out_acc[cur * OUT_DIM + lane], acc);
}

// ---------------- pooling stage 2: divide by count, add bias ----------------
__global__ __launch_bounds__(64) void k_pool2(const float* __restrict__ out_acc,
                                              const int* __restrict__ gids,
                                              const float* __restrict__ b2,
                                              float* __restrict__ out) {
    int gid = blockIdx.x, j = threadIdx.x;
    int lo = 0, hi = N_NODES;
    while (lo < hi) { int mid = (lo + hi) >> 1; if (gids[mid] < gid) lo = mid + 1; else hi = mid; }
    int start = lo;
    hi = N_NODES;
    while (lo < hi) { int mid = (lo + hi) >> 1; if (gids[mid] < gid + 1) lo = mid + 1; else hi = mid; }
    int count = lo - start;
    float b = 0.f;
    #pragma unroll
    for (int t = 0; t < N_ETYPES; ++t) b += b2[t * OUT_DIM + j];
    float c = (float)count;
    out[gid * OUT_DIM + j] = (out_acc[gid * OUT_DIM + j] + c * b) / fmaxf(c, 1.0f);
}

extern "C" void kernel_launch(void* const* d_in, const int* in_sizes, int n_in,
                              void* d_out, int out_size, void* d_ws, size_t ws_size,
                              hipStream_t stream) {
    const float* x    = (const float*)d_in[0];
    const int*   edges= (const int*)d_in[1];
    const int*   gids = (const int*)d_in[2];
    const float* W1   = (const float*)d_in[3];
    const float* b1   = (const float*)d_in[4];
    const float* W2   = (const float*)d_in[5];
    const float* b2   = (const float*)d_in[6];
    float* out = (float*)d_out;

    // word-offset (u32) workspace layout; total 31,335,296 words = 125.3 MB
    // Region sizes audited by max-index:
    //   rowptr: 500,001  csr: 4,000,000 (+63 stage read-over)
    //   xb: 100k*32 u16 = 1,600,000 w   w1t: 128*160 u16 = 10,240 w
    //   w2t: 5*64*128 u16 = 20,480 w    acat: 100k*120 u16 = 6,000,000 w (max idx n*60+59)
    //   g: 5*100k*64 u16 = 16,000,000 w (binned 4,515,840 w aliases head, dead after k_csr)
    //   h2: 100k*64 u16 = 3,200,000 w
    int*   bin_cnt = (int*)d_ws;                          // 0       (256)
    int*   rowptr  = bin_cnt + 256;                       // 256     (500,016)
    int*   csr     = bin_cnt + 500272;                    // 500,272 (4,000,080)
    u16*   xb      = (u16*)(bin_cnt + 4500352);           // 4,500,352 (1,600,000)
    u16*   w1t     = (u16*)(bin_cnt + 6100352);           // 6,100,352 (10,240)
    u16*   w2t     = (u16*)(bin_cnt + 6110592);           // 6,110,592 (20,480)
    float* b1s     = (float*)(bin_cnt + 6131072);         // 6,131,072 (128, pad to 6,131,200)
    u16*   acat    = (u16*)(bin_cnt + 6131200);           // 6,131,200 (6,000,000)
    u16*   g       = (u16*)(bin_cnt + 12131200);          // 12,131,200 (16,000,000)
    int*   binned  = bin_cnt + 12131200;                  // alias over g head (4,515,840)
    u16*   h2      = (u16*)(bin_cnt + 28131200);          // 28,131,200 (3,200,000)
    float* out_acc = (float*)(bin_cnt + 31331200);        // 31,331,200 (4,096)

    hipMemsetAsync(bin_cnt, 0, 256 * sizeof(int), stream);
    hipMemsetAsync(out_acc, 0, NUM_GRAPHS * OUT_DIM * sizeof(float), stream);

    k_prep<<<80, 256, 0, stream>>>(W1, W2, b1, w1t, w2t, b1s);
    k_xb<<<(N_NODES * 32 + 255) / 256, 256, 0, stream>>>(x, xb);
    k_bin<<<(TOT_EDGES + CHUNK - 1) / CHUNK, 256, 0, stream>>>(edges, bin_cnt, binned);
    k_csr<<<NBINS, 256, 0, stream>>>(bin_cnt, binned, rowptr, csr);

    k_gather1<<<dim3(N_NODES / 16, N_ETYPES), 256, 0, stream>>>(
        rowptr, csr, (const u32*)xb, (u32*)acat);

    int nblk = (N_NODES + 63) / 64;
    k_gemm12<<<nblk, 256, 0, stream>>>(acat, w1t, w2t, b1s, g, 0, 5);   // single pass, 5 planes
    k_gather2<<<N_NODES / 8, 256, 0, stream>>>(rowptr, csr, (const u32*)g, (u32*)h2);

    k_pool1<<<(N_NODES + 255) / 256, 256, 0, stream>>>(h2, gids, out_acc);
    k_pool2<<<NUM_GRAPHS, 64, 0, stream>>>(out_acc, gids, b2, out);
}